// Round 10
// baseline (323.271 us; speedup 1.0000x reference)
//
#include <hip/hip_runtime.h>
#include <hip/hip_bf16.h>

#define H 1024
#define SEQ 4096
#define BQ 64   // Kq
#define NB 16   // batch

typedef float f32x4 __attribute__((ext_vector_type(4)));
typedef __bf16 bf16x8 __attribute__((ext_vector_type(8)));

__device__ __forceinline__ void split_bf16(const float* x, bf16x8& hi, bf16x8& lo)
{
    #pragma unroll
    for (int i = 0; i < 8; ++i) {
        float v = x[i];
        __bf16 h = (__bf16)v;
        hi[i] = h;
        lo[i] = (__bf16)(v - (float)h);
    }
}

__device__ __forceinline__ void gload_lds16(const float* g, void* lds)
{
    __builtin_amdgcn_global_load_lds(
        (const __attribute__((address_space(1))) void*)g,
        (__attribute__((address_space(3))) void*)lds, 16, 0, 0);
}

// ---------------------------------------------------------------------------
// MFMA GEMM (BNK-true): C = A @ B^T * scale + bias  (full-K fallback version)
// ---------------------------------------------------------------------------
__global__ __launch_bounds__(256)
void mfma_gemm_bt(const float* __restrict__ A, const float* __restrict__ Bm,
                  const float* __restrict__ bias, float* __restrict__ C, float scale)
{
    const int m0 = blockIdx.x * 64;
    const int n0 = blockIdx.y * 64;
    const int w   = threadIdx.x >> 6;
    const int l   = threadIdx.x & 63;
    const int row = l & 15;
    const int kg  = l >> 4;

    const float* ap = A + (size_t)(m0 + w * 16 + row) * H + kg * 8;
    const float* bp = Bm + (size_t)(n0 + row) * H + kg * 8;

    f32x4 acc[4] = {};
    for (int k0 = 0; k0 < H; k0 += 32) {
        float a8[8];
        *reinterpret_cast<float4*>(&a8[0]) = *reinterpret_cast<const float4*>(ap + k0);
        *reinterpret_cast<float4*>(&a8[4]) = *reinterpret_cast<const float4*>(ap + k0 + 4);
        bf16x8 ahi, alo;
        split_bf16(a8, ahi, alo);
        #pragma unroll
        for (int j = 0; j < 4; ++j) {
            float b8[8];
            const float* bjp = bp + (size_t)j * 16 * H + k0;
            *reinterpret_cast<float4*>(&b8[0]) = *reinterpret_cast<const float4*>(bjp);
            *reinterpret_cast<float4*>(&b8[4]) = *reinterpret_cast<const float4*>(bjp + 4);
            bf16x8 bhi, blo;
            split_bf16(b8, bhi, blo);
            acc[j] = __builtin_amdgcn_mfma_f32_16x16x32_bf16(ahi, bhi, acc[j], 0, 0, 0);
            acc[j] = __builtin_amdgcn_mfma_f32_16x16x32_bf16(ahi, blo, acc[j], 0, 0, 0);
            acc[j] = __builtin_amdgcn_mfma_f32_16x16x32_bf16(alo, bhi, acc[j], 0, 0, 0);
        }
    }
    #pragma unroll
    for (int j = 0; j < 4; ++j) {
        int n = n0 + j * 16 + row;
        float bb = bias ? bias[n] : 0.f;
        #pragma unroll
        for (int r = 0; r < 4; ++r) {
            int m = m0 + w * 16 + kg * 4 + r;
            C[(size_t)m * H + n] = acc[j][r] * scale + bb;
        }
    }
}

// ---------------------------------------------------------------------------
// Split-K (x4) raw-partials GEMM: P[z][m][n] = A[m, z*256..+256) @ B^T
// grid (16,16,4)
// ---------------------------------------------------------------------------
__global__ __launch_bounds__(256)
void mfma_gemm_sk(const float* __restrict__ A, const float* __restrict__ Bm,
                  float* __restrict__ P)
{
    const int m0 = blockIdx.x * 64;
    const int n0 = blockIdx.y * 64;
    const int kb = blockIdx.z * 256;
    const int w   = threadIdx.x >> 6;
    const int l   = threadIdx.x & 63;
    const int row = l & 15;
    const int kg  = l >> 4;

    const float* ap = A + (size_t)(m0 + w * 16 + row) * H + kb + kg * 8;
    const float* bp = Bm + (size_t)(n0 + row) * H + kb + kg * 8;

    f32x4 acc[4] = {};
    for (int k0 = 0; k0 < 256; k0 += 32) {
        float a8[8];
        *reinterpret_cast<float4*>(&a8[0]) = *reinterpret_cast<const float4*>(ap + k0);
        *reinterpret_cast<float4*>(&a8[4]) = *reinterpret_cast<const float4*>(ap + k0 + 4);
        bf16x8 ahi, alo;
        split_bf16(a8, ahi, alo);
        #pragma unroll
        for (int j = 0; j < 4; ++j) {
            float b8[8];
            const float* bjp = bp + (size_t)j * 16 * H + k0;
            *reinterpret_cast<float4*>(&b8[0]) = *reinterpret_cast<const float4*>(bjp);
            *reinterpret_cast<float4*>(&b8[4]) = *reinterpret_cast<const float4*>(bjp + 4);
            bf16x8 bhi, blo;
            split_bf16(b8, bhi, blo);
            acc[j] = __builtin_amdgcn_mfma_f32_16x16x32_bf16(ahi, bhi, acc[j], 0, 0, 0);
            acc[j] = __builtin_amdgcn_mfma_f32_16x16x32_bf16(ahi, blo, acc[j], 0, 0, 0);
            acc[j] = __builtin_amdgcn_mfma_f32_16x16x32_bf16(alo, bhi, acc[j], 0, 0, 0);
        }
    }
    float* pp = P + ((size_t)blockIdx.z << 20);
    #pragma unroll
    for (int j = 0; j < 4; ++j) {
        int n = n0 + j * 16 + row;
        #pragma unroll
        for (int r = 0; r < 4; ++r) {
            int m = m0 + w * 16 + kg * 4 + r;
            pp[(size_t)m * H + n] = acc[j][r];
        }
    }
}

// ---------------------------------------------------------------------------
// combine 4 partials. MODE 0: C = sum*scale + bias (f32). MODE 1: bf16 hi/lo.
// grid 1024 x 256
// ---------------------------------------------------------------------------
template<int MODE>
__global__ __launch_bounds__(256)
void combine4(const float* __restrict__ P, const float* __restrict__ bias,
              float* __restrict__ C, __bf16* __restrict__ Chi,
              __bf16* __restrict__ Clo, float scale)
{
    size_t i = ((size_t)blockIdx.x * 256 + threadIdx.x) * 4;
    f32x4 s = *reinterpret_cast<const f32x4*>(P + i);
    s += *reinterpret_cast<const f32x4*>(P + (1u << 20) + i);
    s += *reinterpret_cast<const f32x4*>(P + (2u << 20) + i);
    s += *reinterpret_cast<const f32x4*>(P + (3u << 20) + i);
    if (MODE == 0) {
        f32x4 bb = *reinterpret_cast<const f32x4*>(bias + (i & 1023));
        f32x4 o;
        #pragma unroll
        for (int j = 0; j < 4; ++j) o[j] = s[j] * scale + bb[j];
        *reinterpret_cast<f32x4*>(C + i) = o;
    } else {
        #pragma unroll
        for (int j = 0; j < 4; ++j) {
            float v = s[j] * scale;
            __bf16 h = (__bf16)v;
            Chi[i + j] = h;
            Clo[i + j] = (__bf16)(v - (float)h);
        }
    }
}

// ---------------------------------------------------------------------------
// Wk transpose: WkT[n][k] = Wk[k][n]
// ---------------------------------------------------------------------------
__global__ __launch_bounds__(256)
void transpose_k(const float* __restrict__ Wk, float* __restrict__ WkT)
{
    __shared__ float tile[64][65];
    const int k0 = blockIdx.x * 64;
    const int n0 = blockIdx.y * 64;
    const int t  = threadIdx.x;
    const int c4 = (t & 15) * 4;
    const int r  = t >> 4;
    #pragma unroll
    for (int p = 0; p < 4; ++p) {
        float4 v = *reinterpret_cast<const float4*>(&Wk[(size_t)(k0 + r + 16 * p) * H + n0 + c4]);
        tile[r + 16 * p][c4 + 0] = v.x;
        tile[r + 16 * p][c4 + 1] = v.y;
        tile[r + 16 * p][c4 + 2] = v.z;
        tile[r + 16 * p][c4 + 3] = v.w;
    }
    __syncthreads();
    #pragma unroll
    for (int p = 0; p < 4; ++p) {
        int rr = r + 16 * p;
        float4 o;
        o.x = tile[c4 + 0][rr];
        o.y = tile[c4 + 1][rr];
        o.z = tile[c4 + 2][rr];
        o.w = tile[c4 + 3][rr];
        *reinterpret_cast<float4*>(&WkT[(size_t)(n0 + rr) * H + k0 + c4]) = o;
    }
}

// ---------------------------------------------------------------------------
// N-proj (BT layout) fallback full-K: -> pre-split bf16 hi/lo [m][n]
// ---------------------------------------------------------------------------
__global__ __launch_bounds__(256)
void ngemm_bt(const float* __restrict__ A, const float* __restrict__ Bm,
              __bf16* __restrict__ Nhi, __bf16* __restrict__ Nlo, float scale)
{
    const int m0 = blockIdx.x * 64;
    const int n0 = blockIdx.y * 64;
    const int w   = threadIdx.x >> 6;
    const int l   = threadIdx.x & 63;
    const int row = l & 15;
    const int kg  = l >> 4;

    const float* ap = A + (size_t)(m0 + w * 16 + row) * H + kg * 8;
    const float* bp = Bm + (size_t)(n0 + row) * H + kg * 8;

    f32x4 acc[4] = {};
    for (int k0 = 0; k0 < H; k0 += 32) {
        float a8[8];
        *reinterpret_cast<float4*>(&a8[0]) = *reinterpret_cast<const float4*>(ap + k0);
        *reinterpret_cast<float4*>(&a8[4]) = *reinterpret_cast<const float4*>(ap + k0 + 4);
        bf16x8 ahi, alo;
        split_bf16(a8, ahi, alo);
        #pragma unroll
        for (int j = 0; j < 4; ++j) {
            float b8[8];
            const float* bjp = bp + (size_t)j * 16 * H + k0;
            *reinterpret_cast<float4*>(&b8[0]) = *reinterpret_cast<const float4*>(bjp);
            *reinterpret_cast<float4*>(&b8[4]) = *reinterpret_cast<const float4*>(bjp + 4);
            bf16x8 bhi, blo;
            split_bf16(b8, bhi, blo);
            acc[j] = __builtin_amdgcn_mfma_f32_16x16x32_bf16(ahi, bhi, acc[j], 0, 0, 0);
            acc[j] = __builtin_amdgcn_mfma_f32_16x16x32_bf16(ahi, blo, acc[j], 0, 0, 0);
            acc[j] = __builtin_amdgcn_mfma_f32_16x16x32_bf16(alo, bhi, acc[j], 0, 0, 0);
        }
    }
    #pragma unroll
    for (int j = 0; j < 4; ++j) {
        int n = n0 + j * 16 + row;
        #pragma unroll
        for (int r = 0; r < 4; ++r) {
            int m = m0 + w * 16 + kg * 4 + r;
            float v = acc[j][r] * scale;
            __bf16 hi = (__bf16)v;
            Nhi[(size_t)m * H + n] = hi;
            Nlo[(size_t)m * H + n] = (__bf16)(v - (float)hi);
        }
    }
}

// ---------------------------------------------------------------------------
// c[b,qi] = scale * dot(q[b,qi,:], bk)
// ---------------------------------------------------------------------------
__global__ __launch_bounds__(256)
void cvec_kernel(const float* __restrict__ q, const float* __restrict__ bk,
                 float* __restrict__ cvec, float scale)
{
    int r = blockIdx.x * 4 + (threadIdx.x >> 6);
    int l = threadIdx.x & 63;
    float s = 0.f;
    #pragma unroll
    for (int i = 0; i < 16; ++i)
        s += q[(size_t)r * H + l + 64 * i] * bk[l + 64 * i];
    #pragma unroll
    for (int off = 32; off; off >>= 1)
        s += __shfl_down(s, off);
    if (l == 0) cvec[r] = s * scale;
}

// ---------------------------------------------------------------------------
// scores[b,s,qi] = sum_h keys[b,s,h]*N[b,qi,h] + c[b,qi]
// 64-k chunks; dbuf XOR-swizzled N LDS (slot = kb ^ (qi&7), write/read same
// involution -> ~2-way = free); prefetch ISSUED AFTER the barrier so it
// drains at the NEXT barrier, covered by compute (m248 order).
// 1024 blocks x 256 thr, XCD swizzle (2 batches per XCD).
// ---------------------------------------------------------------------------
__global__ __launch_bounds__(256)
void scores_mfma(const float* __restrict__ keys,
                 const __bf16* __restrict__ Nhi, const __bf16* __restrict__ Nlo,
                 const float* __restrict__ cvec, float* __restrict__ scores)
{
    const int id = blockIdx.x;
    const int x  = id & 7;
    const int m  = id >> 3;             // 0..127
    const int b  = 2 * x + (m >> 6);
    const int s0 = (m & 63) * 64;

    const int t   = threadIdx.x;
    const int w   = t >> 6;
    const int l   = t & 63;
    const int row = l & 15;
    const int kg  = l >> 4;

    __shared__ __bf16 nshH[2][64][8][8];   // 16 KB
    __shared__ __bf16 nshL[2][64][8][8];   // 16 KB

    const float* ka = keys + ((size_t)b * SEQ + s0 + w * 16 + row) * H + kg * 8;
    const __bf16* nhb = Nhi + (size_t)b * BQ * H;
    const __bf16* nlb = Nlo + (size_t)b * BQ * H;

    const int sqi  = t >> 2;            // 0..63
    const int skb0 = (t & 3) * 2;       // 0,2,4,6
    const int ws0  = (skb0 + 0) ^ (sqi & 7);
    const int ws1  = (skb0 + 1) ^ (sqi & 7);

    float4 kr[2][4];
    bf16x8 nh[2][2], nl[2][2];

    // prologue: chunk 0 into set 0
    #pragma unroll
    for (int ii = 0; ii < 2; ++ii) {
        kr[0][2 * ii + 0] = *reinterpret_cast<const float4*>(ka + ii * 32);
        kr[0][2 * ii + 1] = *reinterpret_cast<const float4*>(ka + ii * 32 + 4);
    }
    #pragma unroll
    for (int u = 0; u < 2; ++u) {
        size_t go = (size_t)sqi * H + (skb0 + u) * 8;
        nh[0][u] = *reinterpret_cast<const bf16x8*>(nhb + go);
        nl[0][u] = *reinterpret_cast<const bf16x8*>(nlb + go);
    }

    f32x4 acc[4] = {};
    #pragma unroll
    for (int c = 0; c < 16; ++c) {
        const int buf = c & 1;
        // write N(c) -> LDS[buf] (swizzled)
        *reinterpret_cast<bf16x8*>(&nshH[buf][sqi][ws0][0]) = nh[buf][0];
        *reinterpret_cast<bf16x8*>(&nshH[buf][sqi][ws1][0]) = nh[buf][1];
        *reinterpret_cast<bf16x8*>(&nshL[buf][sqi][ws0][0]) = nl[buf][0];
        *reinterpret_cast<bf16x8*>(&nshL[buf][sqi][ws1][0]) = nl[buf][1];
        __syncthreads();
        // prefetch chunk c+1 into set buf^1 (drains at NEXT barrier)
        if (c < 15) {
            const int kc = (c + 1) * 64;
            #pragma unroll
            for (int ii = 0; ii < 2; ++ii) {
                kr[buf ^ 1][2 * ii + 0] = *reinterpret_cast<const float4*>(ka + kc + ii * 32);
                kr[buf ^ 1][2 * ii + 1] = *reinterpret_cast<const float4*>(ka + kc + ii * 32 + 4);
            }
            #pragma unroll
            for (int u = 0; u < 2; ++u) {
                size_t go = (size_t)sqi * H + kc + (skb0 + u) * 8;
                nh[buf ^ 1][u] = *reinterpret_cast<const bf16x8*>(nhb + go);
                nl[buf ^ 1][u] = *reinterpret_cast<const bf16x8*>(nlb + go);
            }
        }
        // compute chunk c from kr[buf] + LDS[buf]
        #pragma unroll
        for (int ii = 0; ii < 2; ++ii) {
            float a8[8];
            *reinterpret_cast<float4*>(&a8[0]) = kr[buf][2 * ii + 0];
            *reinterpret_cast<float4*>(&a8[4]) = kr[buf][2 * ii + 1];
            bf16x8 ahi, alo;
            split_bf16(a8, ahi, alo);
            const int kb = ii * 4 + kg;
            const int slot = kb ^ (row & 7);
            #pragma unroll
            for (int j = 0; j < 4; ++j) {
                const int qi = j * 16 + row;
                bf16x8 bhi = *reinterpret_cast<const bf16x8*>(&nshH[buf][qi][slot][0]);
                bf16x8 blo = *reinterpret_cast<const bf16x8*>(&nshL[buf][qi][slot][0]);
                acc[j] = __builtin_amdgcn_mfma_f32_16x16x32_bf16(ahi, bhi, acc[j], 0, 0, 0);
                acc[j] = __builtin_amdgcn_mfma_f32_16x16x32_bf16(ahi, blo, acc[j], 0, 0, 0);
                acc[j] = __builtin_amdgcn_mfma_f32_16x16x32_bf16(alo, bhi, acc[j], 0, 0, 0);
            }
        }
    }

    #pragma unroll
    for (int j = 0; j < 4; ++j) {
        int qi = j * 16 + row;
        float cv = cvec[b * BQ + qi];
        #pragma unroll
        for (int r = 0; r < 4; ++r) {
            int s = s0 + w * 16 + kg * 4 + r;
            scores[((size_t)b * SEQ + s) * BQ + qi] = acc[j][r] + cv;
        }
    }
}

// ---------------------------------------------------------------------------
// softmax over s — partial stats (64-row chunks, 1024 blocks)
// ---------------------------------------------------------------------------
__global__ __launch_bounds__(256)
void sm_partial(const float* __restrict__ scores, float* __restrict__ pmax,
                float* __restrict__ psum)
{
    const int b  = blockIdx.y;
    const int ch = blockIdx.x;       // 64 chunks of 64 rows
    const int t  = threadIdx.x;
    const int qi = t & 63;
    const int g  = t >> 6;
    const float* sb = scores + ((size_t)b * SEQ + ch * 64) * BQ;
    float v[16];
    #pragma unroll
    for (int i = 0; i < 16; ++i)
        v[i] = sb[(size_t)(g + i * 4) * BQ + qi];
    float m = v[0];
    #pragma unroll
    for (int i = 1; i < 16; ++i) m = fmaxf(m, v[i]);
    __shared__ float red[4][64];
    red[g][qi] = m;
    __syncthreads();
    float M = fmaxf(fmaxf(red[0][qi], red[1][qi]), fmaxf(red[2][qi], red[3][qi]));
    float sum = 0.f;
    #pragma unroll
    for (int i = 0; i < 16; ++i) sum += __expf(v[i] - M);
    __syncthreads();
    red[g][qi] = sum;
    __syncthreads();
    if (g == 0) {
        float ssum = red[0][qi] + red[1][qi] + red[2][qi] + red[3][qi];
        pmax[((size_t)b * 64 + ch) * 64 + qi] = M;
        psum[((size_t)b * 64 + ch) * 64 + qi] = ssum;
    }
}

__global__ void sm_combine(const float* __restrict__ pmax,
                           const float* __restrict__ psum,
                           float* __restrict__ gstat)
{
    int b  = blockIdx.x;
    int qi = threadIdx.x; // 64
    float m = -1e30f;
    for (int c = 0; c < 64; ++c)
        m = fmaxf(m, pmax[((size_t)b * 64 + c) * 64 + qi]);
    float s = 0.f;
    for (int c = 0; c < 64; ++c)
        s += psum[((size_t)b * 64 + c) * 64 + qi] *
             __expf(pmax[((size_t)b * 64 + c) * 64 + qi] - m);
    gstat[(size_t)b * 64 + qi] = m;
    gstat[(size_t)(NB + b) * 64 + qi] = 1.f / s;
}

// normalize in place (f32, d_out) + write bf16 TRANSPOSED copy abfT[b][qi][s]
__global__ __launch_bounds__(256)
void sm_norm(float* __restrict__ attn, const float* __restrict__ gstat,
             __hip_bfloat16* __restrict__ abfT)
{
    __shared__ float tile[64][133];
    const int b  = blockIdx.y;
    const int ch = blockIdx.x;
    const int t  = threadIdx.x;
    const int qi = t & 63;
    const int g  = t >> 6;
    const float M   = gstat[(size_t)b * 64 + qi];
    const float inv = gstat[(size_t)(NB + b) * 64 + qi];
    float* sb = attn + ((size_t)b * SEQ + ch * 128) * BQ;
    #pragma unroll 8
    for (int i = 0; i < 32; ++i) {
        int sl = g + i * 4;
        size_t idx = (size_t)sl * BQ + qi;
        float w = __expf(sb[idx] - M) * inv;
        sb[idx] = w;
        tile[qi][sl] = w;
    }
    __syncthreads();
    const int qo = t >> 2;
    const int c  = (t & 3) * 32;
    __hip_bfloat16* dst = abfT + ((size_t)(b * BQ + qo)) * SEQ + ch * 128 + c;
    #pragma unroll
    for (int v = 0; v < 4; ++v) {
        bf16x8 w8;
        #pragma unroll
        for (int e = 0; e < 8; ++e)
            w8[e] = (__bf16)tile[qo][c + v * 8 + e];
        *reinterpret_cast<bf16x8*>(dst + v * 8) = w8;
    }
}

// ---------------------------------------------------------------------------
// Tpart[sc][b][qi][h] = sum_{s in chunk} abfT[b,qi,s] * values[b,s,h]
// values staged via global_load_lds (dbuf, pre-swizzled source col).
// ---------------------------------------------------------------------------
template<int SC>
__global__ __launch_bounds__(256)
void tmat_mfma(const __hip_bfloat16* __restrict__ abfT,
               const float* __restrict__ values,
               float* __restrict__ Tpart)
{
    const int i  = blockIdx.x;
    const int h0 = ((i >> 3) & 7) * 128;
    const int g  = (i & 7) + 8 * (i >> 6);
    const int b  = g / SC;
    const int sc = g % SC;
    const int schunk = SEQ / SC;

    const int w   = threadIdx.x >> 6;
    const int l   = threadIdx.x & 63;
    const int row = l & 15;
    const int kg  = l >> 4;
    const int sbase = sc * schunk;

    __shared__ float vlds[2][32][128];   // 32 KB

    const __hip_bfloat16* ap = abfT + ((size_t)b * BQ + row) * SEQ + sbase + kg * 8;
    const float* vb = values + ((size_t)b * SEQ + sbase) * H + h0;

    const int nk = schunk / 32;

    #define STAGE(buf, k0)                                                     \
        {                                                                      \
            _Pragma("unroll")                                                  \
            for (int ii = 0; ii < 4; ++ii) {                                   \
                int elem = w * 1024 + ii * 256 + l * 4;                        \
                int k    = elem >> 7;                                          \
                int cc   = elem & 127;                                         \
                int csw  = cc ^ ((k >> 3) << 4);                               \
                const float* src = vb + (size_t)((k0) + k) * H + csw;          \
                gload_lds16(src, (void*)(&vlds[buf][0][0] + w * 1024 + ii * 256)); \
            }                                                                  \
        }

    f32x4 acc[4][2] = {};
    STAGE(0, 0);
    __syncthreads();

    for (int ks = 0; ks < nk; ++ks) {
        const int buf = ks & 1;
        if (ks + 1 < nk) STAGE(buf ^ 1, (ks + 1) * 32);
        const int k0 = ks * 32;
        bf16x8 a[4];
        #pragma unroll
        for (int q = 0; q < 4; ++q)
            a[q] = *reinterpret_cast<const bf16x8*>(ap + (size_t)q * 16 * SEQ + k0);
        #pragma unroll
        for (int j = 0; j < 2; ++j) {
            const int col = (w * 32 + j * 16 + row) ^ (kg << 4);
            float b8[8];
            #pragma unroll
            for (int e = 0; e < 8; ++e)
                b8[e] = vlds[buf][kg * 8 + e][col];
            bf16x8 bhi, blo;
            split_bf16(b8, bhi, blo);
            #pragma unroll
            for (int q = 0; q < 4; ++q) {
                acc[q][j] = __builtin_amdgcn_mfma_f32_16x16x32_bf16(a[q], bhi, acc[q][j], 0, 0, 0);
                acc[q][j] = __builtin_amdgcn_mfma_f32_16x16x32_bf16(a[q], blo, acc[q][j], 0, 0, 0);
            }
        }
        __syncthreads();
    }
    #undef STAGE

    float* tp = Tpart + ((size_t)sc * NB + b) * BQ * H;
    #pragma unroll
    for (int q = 0; q < 4; ++q) {
        #pragma unroll
        for (int j = 0; j < 2; ++j) {
            int h = h0 + w * 32 + j * 16 + row;
            #pragma unroll
            for (int r = 0; r < 4; ++r) {
                int qi = q * 16 + kg * 4 + r;
                tp[(size_t)qi * H + h] = acc[q][j][r];
            }
        }
    }
}

// ---------------------------------------------------------------------------
// In-place partial reduction: Tpart[0][i] = sum_p Tpart[p][i]
// ---------------------------------------------------------------------------
template<int SC>
__global__ __launch_bounds__(256)
void tsum_kernel(float* __restrict__ Tpart)
{
    const size_t stride = (size_t)NB * BQ * H;
    size_t i = ((size_t)blockIdx.x * 256 + threadIdx.x) * 4;
    f32x4 s = *reinterpret_cast<const f32x4*>(Tpart + i);
    #pragma unroll
    for (int p = 1; p < SC; ++p)
        s += *reinterpret_cast<const f32x4*>(Tpart + p * stride + i);
    *reinterpret_cast<f32x4*>(Tpart + i) = s;
}

// ---------------------------------------------------------------------------
extern "C" void kernel_launch(void* const* d_in, const int* in_sizes, int n_in,
                              void* d_out, int out_size, void* d_ws, size_t ws_size,
                              hipStream_t stream)
{
    const float* queries = (const float*)d_in[0];
    const float* keys    = (const float*)d_in[1];
    const float* values  = (const float*)d_in[2];
    const float* Wq = (const float*)d_in[3];
    const float* bq = (const float*)d_in[4];
    const float* Wk = (const float*)d_in[5];
    const float* bk = (const float*)d_in[6];
    const float* Wv = (const float*)d_in[7];
    const float* bv = (const float*)d_in[8];

    float* out     = (float*)d_out;
    float* context = out;                          // 16*64*1024 f32
    float* attn    = out + (size_t)NB * BQ * H;    // 16*4096*64 f32

    const bool BIG = (ws_size >= (41ull << 20));
    const int SC = BIG ? 8 : 2;

    char* ws = (char*)d_ws;
    float* q     = (float*)ws;                              // [0,4)
    float* WkT   = (float*)(ws + (4ull << 20));             // [4,8)
    __bf16* Nhi  = (__bf16*)(ws + (8ull << 20));            // [8,10)
    __bf16* Nlo  = (__bf16*)(ws + (10ull << 20));           // [10,12)
    float* GP1   = (float*)(ws + (12ull << 20));            // [12,28) 16 MB partials
    float* GP2   = (float*)(ws + (4ull << 20));             // [4,20) ctx partials (post-tsum)
    float* Tpart = (float*)ws;                              // SC*4 MB
    __hip_bfloat16* abfT = (__hip_bfloat16*)(ws + (size_t)SC * (4ull << 20)); // 8 MB
    char* smalls = ws + (size_t)SC * (4ull << 20) + (8ull << 20);
    float* cvec  = (float*)smalls;                          // 4 KB
    float* gstat = (float*)(smalls + (64u << 10));          // 8 KB
    float* pmax  = (float*)(smalls + (128u << 10));         // 256 KB
    float* psum  = (float*)(smalls + (384u << 10));         // 256 KB

    const float scale = 0.03125f; // 1/sqrt(1024)

    // WkT = Wk^T
    transpose_k<<<dim3(16, 16), 256, 0, stream>>>(Wk, WkT);
    if (BIG) {
        // q = queries @ Wq^T + bq   (split-K4 + combine)
        mfma_gemm_sk<<<dim3(16, 16, 4), 256, 0, stream>>>(queries, Wq, GP1);
        combine4<0><<<1024, 256, 0, stream>>>(GP1, bq, q, nullptr, nullptr, 1.0f);
        // N = (q @ Wk) * scale -> bf16 hi/lo
        mfma_gemm_sk<<<dim3(16, 16, 4), 256, 0, stream>>>(q, WkT, GP1);
        combine4<1><<<1024, 256, 0, stream>>>(GP1, nullptr, nullptr, Nhi, Nlo, scale);
    } else {
        mfma_gemm_bt<<<dim3(16, 16), 256, 0, stream>>>(queries, Wq, bq, q, 1.0f);
        ngemm_bt<<<dim3(16, 16), 256, 0, stream>>>(q, WkT, Nhi, Nlo, scale);
    }
    // c = (q . bk) * scale
    cvec_kernel<<<256, 256, 0, stream>>>(q, bk, cvec, scale);
    // scores
    scores_mfma<<<1024, 256, 0, stream>>>(keys, Nhi, Nlo, cvec, attn);
    // softmax over s
    sm_partial<<<dim3(64, NB), 256, 0, stream>>>(attn, pmax, psum);
    sm_combine<<<NB, 64, 0, stream>>>(pmax, psum, gstat);
    sm_norm<<<dim3(32, NB), 256, 0, stream>>>(attn, gstat, abfT);
    // T partials = attn^T @ values
    if (SC == 8) tmat_mfma<8><<<8 * NB * 8, 256, 0, stream>>>(abfT, values, Tpart);
    else         tmat_mfma<2><<<8 * NB * 2, 256, 0, stream>>>(abfT, values, Tpart);
    // Tsum (in place into partial 0)
    if (SC == 8) tsum_kernel<8><<<1024, 256, 0, stream>>>(Tpart);
    else         tsum_kernel<2><<<1024, 256, 0, stream>>>(Tpart);
    // context = Tsum @ Wv^T + bv
    if (BIG) {
        mfma_gemm_sk<<<dim3(16, 16, 4), 256, 0, stream>>>(Tpart, Wv, GP2);
        combine4<0><<<1024, 256, 0, stream>>>(GP2, bv, context, nullptr, nullptr, 1.0f);
    } else {
        mfma_gemm_bt<<<dim3(16, 16), 256, 0, stream>>>(Tpart, Wv, bv, context, 1.0f);
    }
}

// Round 11
// 287.178 us; speedup vs baseline: 1.1257x; 1.1257x over previous
//
#include <hip/hip_runtime.h>
#include <hip/hip_bf16.h>

#define H 1024
#define SEQ 4096
#define BQ 64   // Kq
#define NB 16   // batch

typedef float f32x4 __attribute__((ext_vector_type(4)));
typedef __bf16 bf16x8 __attribute__((ext_vector_type(8)));

__device__ __forceinline__ void split_bf16(const float* x, bf16x8& hi, bf16x8& lo)
{
    #pragma unroll
    for (int i = 0; i < 8; ++i) {
        float v = x[i];
        __bf16 h = (__bf16)v;
        hi[i] = h;
        lo[i] = (__bf16)(v - (float)h);
    }
}

__device__ __forceinline__ void gload_lds16(const float* g, void* lds)
{
    __builtin_amdgcn_global_load_lds(
        (const __attribute__((address_space(1))) void*)g,
        (__attribute__((address_space(3))) void*)lds, 16, 0, 0);
}

// ---------------------------------------------------------------------------
// MFMA GEMM (BNK-true): C[1024x1024] = A @ B^T * scale + bias (hi/lo, 3 MFMA)
// ---------------------------------------------------------------------------
__global__ __launch_bounds__(256)
void mfma_gemm_bt(const float* __restrict__ A, const float* __restrict__ Bm,
                  const float* __restrict__ bias, float* __restrict__ C, float scale)
{
    const int m0 = blockIdx.x * 64;
    const int n0 = blockIdx.y * 64;
    const int w   = threadIdx.x >> 6;
    const int l   = threadIdx.x & 63;
    const int row = l & 15;
    const int kg  = l >> 4;

    const float* ap = A + (size_t)(m0 + w * 16 + row) * H + kg * 8;
    const float* bp = Bm + (size_t)(n0 + row) * H + kg * 8;

    f32x4 acc[4] = {};
    for (int k0 = 0; k0 < H; k0 += 32) {
        float a8[8];
        *reinterpret_cast<float4*>(&a8[0]) = *reinterpret_cast<const float4*>(ap + k0);
        *reinterpret_cast<float4*>(&a8[4]) = *reinterpret_cast<const float4*>(ap + k0 + 4);
        bf16x8 ahi, alo;
        split_bf16(a8, ahi, alo);
        #pragma unroll
        for (int j = 0; j < 4; ++j) {
            float b8[8];
            const float* bjp = bp + (size_t)j * 16 * H + k0;
            *reinterpret_cast<float4*>(&b8[0]) = *reinterpret_cast<const float4*>(bjp);
            *reinterpret_cast<float4*>(&b8[4]) = *reinterpret_cast<const float4*>(bjp + 4);
            bf16x8 bhi, blo;
            split_bf16(b8, bhi, blo);
            acc[j] = __builtin_amdgcn_mfma_f32_16x16x32_bf16(ahi, bhi, acc[j], 0, 0, 0);
            acc[j] = __builtin_amdgcn_mfma_f32_16x16x32_bf16(ahi, blo, acc[j], 0, 0, 0);
            acc[j] = __builtin_amdgcn_mfma_f32_16x16x32_bf16(alo, bhi, acc[j], 0, 0, 0);
        }
    }
    #pragma unroll
    for (int j = 0; j < 4; ++j) {
        int n = n0 + j * 16 + row;
        float bb = bias ? bias[n] : 0.f;
        #pragma unroll
        for (int r = 0; r < 4; ++r) {
            int m = m0 + w * 16 + kg * 4 + r;
            C[(size_t)m * H + n] = acc[j][r] * scale + bb;
        }
    }
}

// ---------------------------------------------------------------------------
// Wk transpose: WkT[n][k] = Wk[k][n]
// ---------------------------------------------------------------------------
__global__ __launch_bounds__(256)
void transpose_k(const float* __restrict__ Wk, float* __restrict__ WkT)
{
    __shared__ float tile[64][65];
    const int k0 = blockIdx.x * 64;
    const int n0 = blockIdx.y * 64;
    const int t  = threadIdx.x;
    const int c4 = (t & 15) * 4;
    const int r  = t >> 4;
    #pragma unroll
    for (int p = 0; p < 4; ++p) {
        float4 v = *reinterpret_cast<const float4*>(&Wk[(size_t)(k0 + r + 16 * p) * H + n0 + c4]);
        tile[r + 16 * p][c4 + 0] = v.x;
        tile[r + 16 * p][c4 + 1] = v.y;
        tile[r + 16 * p][c4 + 2] = v.z;
        tile[r + 16 * p][c4 + 3] = v.w;
    }
    __syncthreads();
    #pragma unroll
    for (int p = 0; p < 4; ++p) {
        int rr = r + 16 * p;
        float4 o;
        o.x = tile[c4 + 0][rr];
        o.y = tile[c4 + 1][rr];
        o.z = tile[c4 + 2][rr];
        o.w = tile[c4 + 3][rr];
        *reinterpret_cast<float4*>(&WkT[(size_t)(n0 + rr) * H + k0 + c4]) = o;
    }
}

// ---------------------------------------------------------------------------
// N-proj (BT layout): N = (q @ WkT^T) * scale -> pre-split bf16 hi/lo [m][n]
// ---------------------------------------------------------------------------
__global__ __launch_bounds__(256)
void ngemm_bt(const float* __restrict__ A, const float* __restrict__ Bm,
              __bf16* __restrict__ Nhi, __bf16* __restrict__ Nlo, float scale)
{
    const int m0 = blockIdx.x * 64;
    const int n0 = blockIdx.y * 64;
    const int w   = threadIdx.x >> 6;
    const int l   = threadIdx.x & 63;
    const int row = l & 15;
    const int kg  = l >> 4;

    const float* ap = A + (size_t)(m0 + w * 16 + row) * H + kg * 8;
    const float* bp = Bm + (size_t)(n0 + row) * H + kg * 8;

    f32x4 acc[4] = {};
    for (int k0 = 0; k0 < H; k0 += 32) {
        float a8[8];
        *reinterpret_cast<float4*>(&a8[0]) = *reinterpret_cast<const float4*>(ap + k0);
        *reinterpret_cast<float4*>(&a8[4]) = *reinterpret_cast<const float4*>(ap + k0 + 4);
        bf16x8 ahi, alo;
        split_bf16(a8, ahi, alo);
        #pragma unroll
        for (int j = 0; j < 4; ++j) {
            float b8[8];
            const float* bjp = bp + (size_t)j * 16 * H + k0;
            *reinterpret_cast<float4*>(&b8[0]) = *reinterpret_cast<const float4*>(bjp);
            *reinterpret_cast<float4*>(&b8[4]) = *reinterpret_cast<const float4*>(bjp + 4);
            bf16x8 bhi, blo;
            split_bf16(b8, bhi, blo);
            acc[j] = __builtin_amdgcn_mfma_f32_16x16x32_bf16(ahi, bhi, acc[j], 0, 0, 0);
            acc[j] = __builtin_amdgcn_mfma_f32_16x16x32_bf16(ahi, blo, acc[j], 0, 0, 0);
            acc[j] = __builtin_amdgcn_mfma_f32_16x16x32_bf16(alo, bhi, acc[j], 0, 0, 0);
        }
    }
    #pragma unroll
    for (int j = 0; j < 4; ++j) {
        int n = n0 + j * 16 + row;
        #pragma unroll
        for (int r = 0; r < 4; ++r) {
            int m = m0 + w * 16 + kg * 4 + r;
            float v = acc[j][r] * scale;
            __bf16 hi = (__bf16)v;
            Nhi[(size_t)m * H + n] = hi;
            Nlo[(size_t)m * H + n] = (__bf16)(v - (float)hi);
        }
    }
}

// ---------------------------------------------------------------------------
// c[b,qi] = scale * dot(q[b,qi,:], bk)
// ---------------------------------------------------------------------------
__global__ __launch_bounds__(256)
void cvec_kernel(const float* __restrict__ q, const float* __restrict__ bk,
                 float* __restrict__ cvec, float scale)
{
    int r = blockIdx.x * 4 + (threadIdx.x >> 6);
    int l = threadIdx.x & 63;
    float s = 0.f;
    #pragma unroll
    for (int i = 0; i < 16; ++i)
        s += q[(size_t)r * H + l + 64 * i] * bk[l + 64 * i];
    #pragma unroll
    for (int off = 32; off; off >>= 1)
        s += __shfl_down(s, off);
    if (l == 0) cvec[r] = s * scale;
}

// ---------------------------------------------------------------------------
// scores[b,s,qi] = sum_h keys[b,s,h]*N[b,qi,h] + c[b,qi]
// R9 structure (512-thr blocks, 8 waves x 16 s, N LDS-staged per 128-k chunk)
// + ONE change: XOR-swizzled LDS slots (slot = kb ^ (qi&7)) to break the
// 16-way ds_read_b128 bank conflict down to 2-way.
// ---------------------------------------------------------------------------
__global__ __launch_bounds__(512)
void scores_mfma(const float* __restrict__ keys,
                 const __bf16* __restrict__ Nhi, const __bf16* __restrict__ Nlo,
                 const float* __restrict__ cvec, float* __restrict__ scores)
{
    const int id = blockIdx.x;          // 512 blocks
    const int x  = id & 7;
    const int m  = id >> 3;             // 0..63
    const int b  = 2 * x + (m >> 5);    // 2 batches per XCD
    const int s0 = (m & 31) * 128;

    const int t   = threadIdx.x;
    const int w   = t >> 6;             // 0..7
    const int l   = t & 63;
    const int row = l & 15;
    const int kg  = l >> 4;

    __shared__ __bf16 nshH[64][16][8];  // [qi][slot][e], one 128-k chunk (16 KB)
    __shared__ __bf16 nshL[64][16][8];

    const float* ka = keys + ((size_t)b * SEQ + s0 + w * 16 + row) * H + kg * 8;
    const __bf16* nhb = Nhi + (size_t)b * BQ * H;
    const __bf16* nlb = Nlo + (size_t)b * BQ * H;

    // staging: thread t covers (qi = rep*32 + (t>>4), kb = t&15), rep 0..1
    const int sqi = (t >> 4) & 31;
    const int skb = t & 15;
    const int ssl = skb ^ (sqi & 7);    // swizzled slot ((rep*32+sqi)&7 == sqi&7)

    f32x4 acc[4] = {};
    for (int c = 0; c < 8; ++c) {
        const int kc = c * 128;
        // 1) keys chunk into regs
        float4 kr[8];
        #pragma unroll
        for (int ii = 0; ii < 4; ++ii) {
            kr[2 * ii + 0] = *reinterpret_cast<const float4*>(ka + kc + ii * 32);
            kr[2 * ii + 1] = *reinterpret_cast<const float4*>(ka + kc + ii * 32 + 4);
        }
        // 2) N chunk into regs
        bf16x8 nh[2], nl[2];
        #pragma unroll
        for (int rep = 0; rep < 2; ++rep) {
            size_t go = (size_t)(rep * 32 + sqi) * H + kc + skb * 8;
            nh[rep] = *reinterpret_cast<const bf16x8*>(nhb + go);
            nl[rep] = *reinterpret_cast<const bf16x8*>(nlb + go);
        }
        // 3) wait for previous chunk's readers, write LDS (swizzled), publish
        __syncthreads();
        #pragma unroll
        for (int rep = 0; rep < 2; ++rep) {
            *reinterpret_cast<bf16x8*>(&nshH[rep * 32 + sqi][ssl][0]) = nh[rep];
            *reinterpret_cast<bf16x8*>(&nshL[rep * 32 + sqi][ssl][0]) = nl[rep];
        }
        __syncthreads();
        // 4) compute 4 k-iters (read with the same swizzle involution)
        #pragma unroll
        for (int ii = 0; ii < 4; ++ii) {
            float a8[8];
            *reinterpret_cast<float4*>(&a8[0]) = kr[2 * ii + 0];
            *reinterpret_cast<float4*>(&a8[4]) = kr[2 * ii + 1];
            bf16x8 ahi, alo;
            split_bf16(a8, ahi, alo);
            const int kb = ii * 4 + kg;
            const int slot = kb ^ (row & 7);
            #pragma unroll
            for (int j = 0; j < 4; ++j) {
                const int qi = j * 16 + row;
                bf16x8 bhi = *reinterpret_cast<const bf16x8*>(&nshH[qi][slot][0]);
                bf16x8 blo = *reinterpret_cast<const bf16x8*>(&nshL[qi][slot][0]);
                acc[j] = __builtin_amdgcn_mfma_f32_16x16x32_bf16(ahi, bhi, acc[j], 0, 0, 0);
                acc[j] = __builtin_amdgcn_mfma_f32_16x16x32_bf16(ahi, blo, acc[j], 0, 0, 0);
                acc[j] = __builtin_amdgcn_mfma_f32_16x16x32_bf16(alo, bhi, acc[j], 0, 0, 0);
            }
        }
    }
    #pragma unroll
    for (int j = 0; j < 4; ++j) {
        int qi = j * 16 + row;
        float cv = cvec[b * BQ + qi];
        #pragma unroll
        for (int r = 0; r < 4; ++r) {
            int s = s0 + w * 16 + kg * 4 + r;
            scores[((size_t)b * SEQ + s) * BQ + qi] = acc[j][r] + cv;
        }
    }
}

// ---------------------------------------------------------------------------
// softmax over s — partial stats (128-row chunks)
// ---------------------------------------------------------------------------
__global__ __launch_bounds__(256)
void sm_partial(const float* __restrict__ scores, float* __restrict__ pmax,
                float* __restrict__ psum)
{
    const int b  = blockIdx.y;
    const int ch = blockIdx.x;
    const int t  = threadIdx.x;
    const int qi = t & 63;
    const int g  = t >> 6;
    const float* sb = scores + ((size_t)b * SEQ + ch * 128) * BQ;
    float v[32];
    #pragma unroll
    for (int i = 0; i < 32; ++i)
        v[i] = sb[(size_t)(g + i * 4) * BQ + qi];
    float m = v[0];
    #pragma unroll
    for (int i = 1; i < 32; ++i) m = fmaxf(m, v[i]);
    __shared__ float red[4][64];
    red[g][qi] = m;
    __syncthreads();
    float M = fmaxf(fmaxf(red[0][qi], red[1][qi]), fmaxf(red[2][qi], red[3][qi]));
    float sum = 0.f;
    #pragma unroll
    for (int i = 0; i < 32; ++i) sum += __expf(v[i] - M);
    __syncthreads();
    red[g][qi] = sum;
    __syncthreads();
    if (g == 0) {
        float ssum = red[0][qi] + red[1][qi] + red[2][qi] + red[3][qi];
        pmax[((size_t)b * 32 + ch) * 64 + qi] = M;
        psum[((size_t)b * 32 + ch) * 64 + qi] = ssum;
    }
}

__global__ void sm_combine(const float* __restrict__ pmax,
                           const float* __restrict__ psum,
                           float* __restrict__ gstat)
{
    int b  = blockIdx.x;
    int qi = threadIdx.x; // 64
    float m = -1e30f;
    for (int c = 0; c < 32; ++c)
        m = fmaxf(m, pmax[((size_t)b * 32 + c) * 64 + qi]);
    float s = 0.f;
    for (int c = 0; c < 32; ++c)
        s += psum[((size_t)b * 32 + c) * 64 + qi] *
             __expf(pmax[((size_t)b * 32 + c) * 64 + qi] - m);
    gstat[(size_t)b * 64 + qi] = m;
    gstat[(size_t)(NB + b) * 64 + qi] = 1.f / s;
}

// normalize in place (f32, d_out) + write bf16 TRANSPOSED copy abfT[b][qi][s]
__global__ __launch_bounds__(256)
void sm_norm(float* __restrict__ attn, const float* __restrict__ gstat,
             __hip_bfloat16* __restrict__ abfT)
{
    __shared__ float tile[64][133];
    const int b  = blockIdx.y;
    const int ch = blockIdx.x;
    const int t  = threadIdx.x;
    const int qi = t & 63;
    const int g  = t >> 6;
    const float M   = gstat[(size_t)b * 64 + qi];
    const float inv = gstat[(size_t)(NB + b) * 64 + qi];
    float* sb = attn + ((size_t)b * SEQ + ch * 128) * BQ;
    #pragma unroll 8
    for (int i = 0; i < 32; ++i) {
        int sl = g + i * 4;
        size_t idx = (size_t)sl * BQ + qi;
        float w = __expf(sb[idx] - M) * inv;
        sb[idx] = w;
        tile[qi][sl] = w;
    }
    __syncthreads();
    const int qo = t >> 2;
    const int c  = (t & 3) * 32;
    __hip_bfloat16* dst = abfT + ((size_t)(b * BQ + qo)) * SEQ + ch * 128 + c;
    #pragma unroll
    for (int v = 0; v < 4; ++v) {
        bf16x8 w8;
        #pragma unroll
        for (int e = 0; e < 8; ++e)
            w8[e] = (__bf16)tile[qo][c + v * 8 + e];
        *reinterpret_cast<bf16x8*>(dst + v * 8) = w8;
    }
}

// ---------------------------------------------------------------------------
// Tpart[sc][b][qi][h] = sum_{s in chunk} abfT[b,qi,s] * values[b,s,h]
// values staged via global_load_lds into [32][128] f32 tiles (dbuf), source
// pre-swizzled col^(kg<<4) so fragment ds_reads are <=2-way (free).
// XCD-grouped 1D grid.
// ---------------------------------------------------------------------------
template<int SC>
__global__ __launch_bounds__(256)
void tmat_mfma(const __hip_bfloat16* __restrict__ abfT,
               const float* __restrict__ values,
               float* __restrict__ Tpart)
{
    const int i  = blockIdx.x;
    const int h0 = ((i >> 3) & 7) * 128;
    const int g  = (i & 7) + 8 * (i >> 6);
    const int b  = g / SC;
    const int sc = g % SC;
    const int schunk = SEQ / SC;

    const int w   = threadIdx.x >> 6;
    const int l   = threadIdx.x & 63;
    const int row = l & 15;
    const int kg  = l >> 4;
    const int sbase = sc * schunk;

    __shared__ float vlds[2][32][128];   // 32 KB

    const __hip_bfloat16* ap = abfT + ((size_t)b * BQ + row) * SEQ + sbase + kg * 8;
    const float* vb = values + ((size_t)b * SEQ + sbase) * H + h0;

    const int nk = schunk / 32;

    #define STAGE(buf, k0)                                                     \
        {                                                                      \
            _Pragma("unroll")                                                  \
            for (int ii = 0; ii < 4; ++ii) {                                   \
                int elem = w * 1024 + ii * 256 + l * 4;                        \
                int k    = elem >> 7;                                          \
                int cc   = elem & 127;                                         \
                int csw  = cc ^ ((k >> 3) << 4);                               \
                const float* src = vb + (size_t)((k0) + k) * H + csw;          \
                gload_lds16(src, (void*)(&vlds[buf][0][0] + w * 1024 + ii * 256)); \
            }                                                                  \
        }

    f32x4 acc[4][2] = {};
    STAGE(0, 0);
    __syncthreads();

    for (int ks = 0; ks < nk; ++ks) {
        const int buf = ks & 1;
        if (ks + 1 < nk) STAGE(buf ^ 1, (ks + 1) * 32);
        const int k0 = ks * 32;
        bf16x8 a[4];
        #pragma unroll
        for (int q = 0; q < 4; ++q)
            a[q] = *reinterpret_cast<const bf16x8*>(ap + (size_t)q * 16 * SEQ + k0);
        #pragma unroll
        for (int j = 0; j < 2; ++j) {
            const int col = (w * 32 + j * 16 + row) ^ (kg << 4);
            float b8[8];
            #pragma unroll
            for (int e = 0; e < 8; ++e)
                b8[e] = vlds[buf][kg * 8 + e][col];
            bf16x8 bhi, blo;
            split_bf16(b8, bhi, blo);
            #pragma unroll
            for (int q = 0; q < 4; ++q) {
                acc[q][j] = __builtin_amdgcn_mfma_f32_16x16x32_bf16(a[q], bhi, acc[q][j], 0, 0, 0);
                acc[q][j] = __builtin_amdgcn_mfma_f32_16x16x32_bf16(a[q], blo, acc[q][j], 0, 0, 0);
            }
        }
        __syncthreads();
    }
    #undef STAGE

    float* tp = Tpart + ((size_t)sc * NB + b) * BQ * H;
    #pragma unroll
    for (int q = 0; q < 4; ++q) {
        #pragma unroll
        for (int j = 0; j < 2; ++j) {
            int h = h0 + w * 32 + j * 16 + row;
            #pragma unroll
            for (int r = 0; r < 4; ++r) {
                int qi = q * 16 + kg * 4 + r;
                tp[(size_t)qi * H + h] = acc[q][j][r];
            }
        }
    }
}

// ---------------------------------------------------------------------------
// In-place partial reduction: Tpart[0][i] = sum_p Tpart[p][i]
// ---------------------------------------------------------------------------
template<int SC>
__global__ __launch_bounds__(256)
void tsum_kernel(float* __restrict__ Tpart)
{
    const size_t stride = (size_t)NB * BQ * H;
    size_t i = ((size_t)blockIdx.x * 256 + threadIdx.x) * 4;
    f32x4 s = *reinterpret_cast<const f32x4*>(Tpart + i);
    #pragma unroll
    for (int p = 1; p < SC; ++p)
        s += *reinterpret_cast<const f32x4*>(Tpart + p * stride + i);
    *reinterpret_cast<f32x4*>(Tpart + i) = s;
}

// ---------------------------------------------------------------------------
extern "C" void kernel_launch(void* const* d_in, const int* in_sizes, int n_in,
                              void* d_out, int out_size, void* d_ws, size_t ws_size,
                              hipStream_t stream)
{
    const float* queries = (const float*)d_in[0];
    const float* keys    = (const float*)d_in[1];
    const float* values  = (const float*)d_in[2];
    const float* Wq = (const float*)d_in[3];
    const float* bq = (const float*)d_in[4];
    const float* Wk = (const float*)d_in[5];
    const float* bk = (const float*)d_in[6];
    const float* Wv = (const float*)d_in[7];
    const float* bv = (const float*)d_in[8];

    float* out     = (float*)d_out;
    float* context = out;                          // 16*64*1024 f32
    float* attn    = out + (size_t)NB * BQ * H;    // 16*4096*64 f32

    const int SC = (ws_size >= (41ull << 20)) ? 8 : 2;

    char* ws = (char*)d_ws;
    float* q     = (float*)ws;                              // 4 MB  [0,4)
    float* WkT   = (float*)(ws + (4ull << 20));             // 4 MB  [4,8)
    __bf16* Nhi  = (__bf16*)(ws + (8ull << 20));            // 2 MB  [8,10)
    __bf16* Nlo  = (__bf16*)(ws + (10ull << 20));           // 2 MB  [10,12)
    float* Tpart = (float*)ws;                              // SC*4 MB (overlaps q/WkT/N, dead by tmat)
    __hip_bfloat16* abfT = (__hip_bfloat16*)(ws + (size_t)SC * (4ull << 20)); // 8 MB
    char* smalls = ws + (size_t)SC * (4ull << 20) + (8ull << 20);
    float* cvec  = (float*)smalls;                          // 4 KB
    float* gstat = (float*)(smalls + (64u << 10));          // 8 KB
    float* pmax  = (float*)(smalls + (128u << 10));         // 128 KB
    float* psum  = (float*)(smalls + (512u << 10));         // 128 KB

    const float scale = 0.03125f; // 1/sqrt(1024)

    // WkT = Wk^T
    transpose_k<<<dim3(16, 16), 256, 0, stream>>>(Wk, WkT);
    // q = queries @ Wq^T + bq
    mfma_gemm_bt<<<dim3(16, 16), 256, 0, stream>>>(queries, Wq, bq, q, 1.0f);
    // N = (q @ Wk) * scale  -> pre-split bf16 hi/lo (BT layout via WkT)
    ngemm_bt<<<dim3(16, 16), 256, 0, stream>>>(q, WkT, Nhi, Nlo, scale);
    // c = (q . bk) * scale
    cvec_kernel<<<256, 256, 0, stream>>>(q, bk, cvec, scale);
    // scores (512 blocks x 512 threads, R9 structure + LDS XOR swizzle)
    scores_mfma<<<512, 512, 0, stream>>>(keys, Nhi, Nlo, cvec, attn);
    // softmax over s
    sm_partial<<<dim3(32, NB), 256, 0, stream>>>(attn, pmax, psum);
    sm_combine<<<NB, 64, 0, stream>>>(pmax, psum, gstat);
    sm_norm<<<dim3(32, NB), 256, 0, stream>>>(attn, gstat, abfT);
    // T partials = attn^T @ values (MFMA, gload_lds-staged V, split-S, XCD-grouped)
    if (SC == 8) tmat_mfma<8><<<8 * NB * 8, 256, 0, stream>>>(abfT, values, Tpart);
    else         tmat_mfma<2><<<8 * NB * 2, 256, 0, stream>>>(abfT, values, Tpart);
    // Tsum (in place into partial 0)
    if (SC == 8) tsum_kernel<8><<<1024, 256, 0, stream>>>(Tpart);
    else         tsum_kernel<2><<<1024, 256, 0, stream>>>(Tpart);
    // context = Tsum @ Wv^T + bv
    mfma_gemm_bt<<<dim3(16, 16), 256, 0, stream>>>(Tpart, Wv, bv, context, 1.0f);
}

// Round 12
// 284.802 us; speedup vs baseline: 1.1351x; 1.0083x over previous
//
#include <hip/hip_runtime.h>
#include <hip/hip_bf16.h>

#define H 1024
#define SEQ 4096
#define BQ 64   // Kq
#define NB 16   // batch

typedef float f32x4 __attribute__((ext_vector_type(4)));
typedef __bf16 bf16x8 __attribute__((ext_vector_type(8)));

__device__ __forceinline__ void split_bf16(const float* x, bf16x8& hi, bf16x8& lo)
{
    #pragma unroll
    for (int i = 0; i < 8; ++i) {
        float v = x[i];
        __bf16 h = (__bf16)v;
        hi[i] = h;
        lo[i] = (__bf16)(v - (float)h);
    }
}

__device__ __forceinline__ void gload_lds16(const float* g, void* lds)
{
    __builtin_amdgcn_global_load_lds(
        (const __attribute__((address_space(1))) void*)g,
        (__attribute__((address_space(3))) void*)lds, 16, 0, 0);
}

// ---------------------------------------------------------------------------
// 512-thread split-K(x2)-in-block MFMA GEMM (BNK-true): C = A @ B^T
// waves 0-3: k in [0,512); waves 4-7: [512,1024). LDS f32x4 reduce.
// MODE 0: C = sum*scale + bias (f32). MODE 1: bf16 hi/lo out (Nhi/Nlo).
// ---------------------------------------------------------------------------
template<int MODE>
__global__ __launch_bounds__(512)
void gemm_bt_512(const float* __restrict__ A, const float* __restrict__ Bm,
                 const float* __restrict__ bias, float* __restrict__ C,
                 __bf16* __restrict__ Nhi, __bf16* __restrict__ Nlo, float scale)
{
    const int m0 = blockIdx.x * 64;
    const int n0 = blockIdx.y * 64;
    const int t   = threadIdx.x;
    const int w   = t >> 6;
    const int wm  = w & 3;      // m-subtile
    const int kh  = w >> 2;     // k-half
    const int l   = t & 63;
    const int row = l & 15;
    const int kg  = l >> 4;

    const float* ap = A + (size_t)(m0 + wm * 16 + row) * H + kh * 512 + kg * 8;
    const float* bp = Bm + (size_t)(n0 + row) * H + kh * 512 + kg * 8;

    f32x4 acc[4] = {};
    for (int k0 = 0; k0 < 512; k0 += 32) {
        float a8[8];
        *reinterpret_cast<float4*>(&a8[0]) = *reinterpret_cast<const float4*>(ap + k0);
        *reinterpret_cast<float4*>(&a8[4]) = *reinterpret_cast<const float4*>(ap + k0 + 4);
        bf16x8 ahi, alo;
        split_bf16(a8, ahi, alo);
        #pragma unroll
        for (int j = 0; j < 4; ++j) {
            float b8[8];
            const float* bjp = bp + (size_t)j * 16 * H + k0;
            *reinterpret_cast<float4*>(&b8[0]) = *reinterpret_cast<const float4*>(bjp);
            *reinterpret_cast<float4*>(&b8[4]) = *reinterpret_cast<const float4*>(bjp + 4);
            bf16x8 bhi, blo;
            split_bf16(b8, bhi, blo);
            acc[j] = __builtin_amdgcn_mfma_f32_16x16x32_bf16(ahi, bhi, acc[j], 0, 0, 0);
            acc[j] = __builtin_amdgcn_mfma_f32_16x16x32_bf16(ahi, blo, acc[j], 0, 0, 0);
            acc[j] = __builtin_amdgcn_mfma_f32_16x16x32_bf16(alo, bhi, acc[j], 0, 0, 0);
        }
    }

    __shared__ f32x4 red[4][4][64];   // [wm][j][lane] from kh==1 waves (16 KB)
    if (kh == 1) {
        #pragma unroll
        for (int j = 0; j < 4; ++j) red[wm][j][l] = acc[j];
    }
    __syncthreads();
    if (kh == 0) {
        #pragma unroll
        for (int j = 0; j < 4; ++j) {
            f32x4 s = acc[j] + red[wm][j][l];
            int n = n0 + j * 16 + row;
            if (MODE == 0) {
                float bb = bias ? bias[n] : 0.f;
                #pragma unroll
                for (int r = 0; r < 4; ++r) {
                    int m = m0 + wm * 16 + kg * 4 + r;
                    C[(size_t)m * H + n] = s[r] * scale + bb;
                }
            } else {
                #pragma unroll
                for (int r = 0; r < 4; ++r) {
                    int m = m0 + wm * 16 + kg * 4 + r;
                    float v = s[r] * scale;
                    __bf16 hi = (__bf16)v;
                    Nhi[(size_t)m * H + n] = hi;
                    Nlo[(size_t)m * H + n] = (__bf16)(v - (float)hi);
                }
            }
        }
    }
}

// ---------------------------------------------------------------------------
// Wk transpose: WkT[n][k] = Wk[k][n]
// ---------------------------------------------------------------------------
__global__ __launch_bounds__(256)
void transpose_k(const float* __restrict__ Wk, float* __restrict__ WkT)
{
    __shared__ float tile[64][65];
    const int k0 = blockIdx.x * 64;
    const int n0 = blockIdx.y * 64;
    const int t  = threadIdx.x;
    const int c4 = (t & 15) * 4;
    const int r  = t >> 4;
    #pragma unroll
    for (int p = 0; p < 4; ++p) {
        float4 v = *reinterpret_cast<const float4*>(&Wk[(size_t)(k0 + r + 16 * p) * H + n0 + c4]);
        tile[r + 16 * p][c4 + 0] = v.x;
        tile[r + 16 * p][c4 + 1] = v.y;
        tile[r + 16 * p][c4 + 2] = v.z;
        tile[r + 16 * p][c4 + 3] = v.w;
    }
    __syncthreads();
    #pragma unroll
    for (int p = 0; p < 4; ++p) {
        int rr = r + 16 * p;
        float4 o;
        o.x = tile[c4 + 0][rr];
        o.y = tile[c4 + 1][rr];
        o.z = tile[c4 + 2][rr];
        o.w = tile[c4 + 3][rr];
        *reinterpret_cast<float4*>(&WkT[(size_t)(n0 + rr) * H + k0 + c4]) = o;
    }
}

// ---------------------------------------------------------------------------
// c[b,qi] = scale * dot(q[b,qi,:], bk)
// ---------------------------------------------------------------------------
__global__ __launch_bounds__(256)
void cvec_kernel(const float* __restrict__ q, const float* __restrict__ bk,
                 float* __restrict__ cvec, float scale)
{
    int r = blockIdx.x * 4 + (threadIdx.x >> 6);
    int l = threadIdx.x & 63;
    float s = 0.f;
    #pragma unroll
    for (int i = 0; i < 16; ++i)
        s += q[(size_t)r * H + l + 64 * i] * bk[l + 64 * i];
    #pragma unroll
    for (int off = 32; off; off >>= 1)
        s += __shfl_down(s, off);
    if (l == 0) cvec[r] = s * scale;
}

// ---------------------------------------------------------------------------
// scores[b,s,qi] = sum_h keys[b,s,h]*N[b,qi,h] + c[b,qi]
// R11 structure (512-thr, 8 waves x 16 s, XOR-swizzled N LDS) + FUSED
// per-128-row-chunk softmax partial stats (max/sum) from the accumulators.
// ---------------------------------------------------------------------------
__global__ __launch_bounds__(512)
void scores_mfma(const float* __restrict__ keys,
                 const __bf16* __restrict__ Nhi, const __bf16* __restrict__ Nlo,
                 const float* __restrict__ cvec, float* __restrict__ scores,
                 float* __restrict__ pmax, float* __restrict__ psum)
{
    const int id = blockIdx.x;          // 512 blocks
    const int x  = id & 7;
    const int m  = id >> 3;             // 0..63
    const int b  = 2 * x + (m >> 5);    // 2 batches per XCD
    const int ch = m & 31;
    const int s0 = ch * 128;

    const int t   = threadIdx.x;
    const int w   = t >> 6;             // 0..7
    const int l   = t & 63;
    const int row = l & 15;
    const int kg  = l >> 4;

    __shared__ __bf16 nshH[64][16][8];  // [qi][slot][e] (16 KB)
    __shared__ __bf16 nshL[64][16][8];
    __shared__ float redm[8][64];       // 2 KB

    const float* ka = keys + ((size_t)b * SEQ + s0 + w * 16 + row) * H + kg * 8;
    const __bf16* nhb = Nhi + (size_t)b * BQ * H;
    const __bf16* nlb = Nlo + (size_t)b * BQ * H;

    const int sqi = (t >> 4) & 31;
    const int skb = t & 15;
    const int ssl = skb ^ (sqi & 7);

    f32x4 acc[4] = {};
    for (int c = 0; c < 8; ++c) {
        const int kc = c * 128;
        float4 kr[8];
        #pragma unroll
        for (int ii = 0; ii < 4; ++ii) {
            kr[2 * ii + 0] = *reinterpret_cast<const float4*>(ka + kc + ii * 32);
            kr[2 * ii + 1] = *reinterpret_cast<const float4*>(ka + kc + ii * 32 + 4);
        }
        bf16x8 nh[2], nl[2];
        #pragma unroll
        for (int rep = 0; rep < 2; ++rep) {
            size_t go = (size_t)(rep * 32 + sqi) * H + kc + skb * 8;
            nh[rep] = *reinterpret_cast<const bf16x8*>(nhb + go);
            nl[rep] = *reinterpret_cast<const bf16x8*>(nlb + go);
        }
        __syncthreads();
        #pragma unroll
        for (int rep = 0; rep < 2; ++rep) {
            *reinterpret_cast<bf16x8*>(&nshH[rep * 32 + sqi][ssl][0]) = nh[rep];
            *reinterpret_cast<bf16x8*>(&nshL[rep * 32 + sqi][ssl][0]) = nl[rep];
        }
        __syncthreads();
        #pragma unroll
        for (int ii = 0; ii < 4; ++ii) {
            float a8[8];
            *reinterpret_cast<float4*>(&a8[0]) = kr[2 * ii + 0];
            *reinterpret_cast<float4*>(&a8[4]) = kr[2 * ii + 1];
            bf16x8 ahi, alo;
            split_bf16(a8, ahi, alo);
            const int kb = ii * 4 + kg;
            const int slot = kb ^ (row & 7);
            #pragma unroll
            for (int j = 0; j < 4; ++j) {
                const int qi = j * 16 + row;
                bf16x8 bhi = *reinterpret_cast<const bf16x8*>(&nshH[qi][slot][0]);
                bf16x8 blo = *reinterpret_cast<const bf16x8*>(&nshL[qi][slot][0]);
                acc[j] = __builtin_amdgcn_mfma_f32_16x16x32_bf16(ahi, bhi, acc[j], 0, 0, 0);
                acc[j] = __builtin_amdgcn_mfma_f32_16x16x32_bf16(ahi, blo, acc[j], 0, 0, 0);
                acc[j] = __builtin_amdgcn_mfma_f32_16x16x32_bf16(alo, bhi, acc[j], 0, 0, 0);
            }
        }
    }

    // epilogue: add cvec, write scores
    #pragma unroll
    for (int j = 0; j < 4; ++j) {
        int qi = j * 16 + row;
        float cv = cvec[b * BQ + qi];
        #pragma unroll
        for (int r = 0; r < 4; ++r) {
            acc[j][r] += cv;
            int s = s0 + w * 16 + kg * 4 + r;
            scores[((size_t)b * SEQ + s) * BQ + qi] = acc[j][r];
        }
    }
    // fused partial stats over this block's 128 s-rows
    float mj[4];
    #pragma unroll
    for (int j = 0; j < 4; ++j) {
        float mm = fmaxf(fmaxf(acc[j][0], acc[j][1]), fmaxf(acc[j][2], acc[j][3]));
        mm = fmaxf(mm, __shfl_xor(mm, 16));
        mm = fmaxf(mm, __shfl_xor(mm, 32));
        mj[j] = mm;                      // wave-level max for qi=j*16+row
    }
    __syncthreads();                     // LDS (nsh) done; reuse redm safely
    if (kg == 0) {
        #pragma unroll
        for (int j = 0; j < 4; ++j) redm[w][j * 16 + row] = mj[j];
    }
    __syncthreads();
    float Mj[4];
    #pragma unroll
    for (int j = 0; j < 4; ++j) {
        const int qi = j * 16 + row;
        float M = redm[0][qi];
        #pragma unroll
        for (int ww = 1; ww < 8; ++ww) M = fmaxf(M, redm[ww][qi]);
        Mj[j] = M;
    }
    float sj[4];
    #pragma unroll
    for (int j = 0; j < 4; ++j) {
        float s = 0.f;
        #pragma unroll
        for (int r = 0; r < 4; ++r) s += __expf(acc[j][r] - Mj[j]);
        s += __shfl_xor(s, 16);
        s += __shfl_xor(s, 32);
        sj[j] = s;
    }
    __syncthreads();
    if (kg == 0) {
        #pragma unroll
        for (int j = 0; j < 4; ++j) redm[w][j * 16 + row] = sj[j];
    }
    __syncthreads();
    if (w == 0 && kg == 0) {
        #pragma unroll
        for (int j = 0; j < 4; ++j) {
            const int qi = j * 16 + row;
            float ss = 0.f;
            #pragma unroll
            for (int ww = 0; ww < 8; ++ww) ss += redm[ww][qi];
            pmax[((size_t)b * 32 + ch) * 64 + qi] = Mj[j];
            psum[((size_t)b * 32 + ch) * 64 + qi] = ss;
        }
    }
}

// ---------------------------------------------------------------------------
// combine 32 chunk-stats per (b,qi)
// ---------------------------------------------------------------------------
__global__ void sm_combine(const float* __restrict__ pmax,
                           const float* __restrict__ psum,
                           float* __restrict__ gstat)
{
    int b  = blockIdx.x;
    int qi = threadIdx.x; // 64
    float m = -1e30f;
    for (int c = 0; c < 32; ++c)
        m = fmaxf(m, pmax[((size_t)b * 32 + c) * 64 + qi]);
    float s = 0.f;
    for (int c = 0; c < 32; ++c)
        s += psum[((size_t)b * 32 + c) * 64 + qi] *
             __expf(pmax[((size_t)b * 32 + c) * 64 + qi] - m);
    gstat[(size_t)b * 64 + qi] = m;
    gstat[(size_t)(NB + b) * 64 + qi] = 1.f / s;
}

// normalize in place (f32, d_out) + write bf16 TRANSPOSED copy abfT[b][qi][s]
__global__ __launch_bounds__(256)
void sm_norm(float* __restrict__ attn, const float* __restrict__ gstat,
             __hip_bfloat16* __restrict__ abfT)
{
    __shared__ float tile[64][133];
    const int b  = blockIdx.y;
    const int ch = blockIdx.x;
    const int t  = threadIdx.x;
    const int qi = t & 63;
    const int g  = t >> 6;
    const float M   = gstat[(size_t)b * 64 + qi];
    const float inv = gstat[(size_t)(NB + b) * 64 + qi];
    float* sb = attn + ((size_t)b * SEQ + ch * 128) * BQ;
    #pragma unroll 8
    for (int i = 0; i < 32; ++i) {
        int sl = g + i * 4;
        size_t idx = (size_t)sl * BQ + qi;
        float w = __expf(sb[idx] - M) * inv;
        sb[idx] = w;
        tile[qi][sl] = w;
    }
    __syncthreads();
    const int qo = t >> 2;
    const int c  = (t & 3) * 32;
    __hip_bfloat16* dst = abfT + ((size_t)(b * BQ + qo)) * SEQ + ch * 128 + c;
    #pragma unroll
    for (int v = 0; v < 4; ++v) {
        bf16x8 w8;
        #pragma unroll
        for (int e = 0; e < 8; ++e)
            w8[e] = (__bf16)tile[qo][c + v * 8 + e];
        *reinterpret_cast<bf16x8*>(dst + v * 8) = w8;
    }
}

// ---------------------------------------------------------------------------
// Tpart[sc][b][qi][h] = sum_{s in chunk} abfT[b,qi,s] * values[b,s,h]
// values staged via global_load_lds (dbuf, pre-swizzled source col).
// ---------------------------------------------------------------------------
template<int SC>
__global__ __launch_bounds__(256)
void tmat_mfma(const __hip_bfloat16* __restrict__ abfT,
               const float* __restrict__ values,
               float* __restrict__ Tpart)
{
    const int i  = blockIdx.x;
    const int h0 = ((i >> 3) & 7) * 128;
    const int g  = (i & 7) + 8 * (i >> 6);
    const int b  = g / SC;
    const int sc = g % SC;
    const int schunk = SEQ / SC;

    const int w   = threadIdx.x >> 6;
    const int l   = threadIdx.x & 63;
    const int row = l & 15;
    const int kg  = l >> 4;
    const int sbase = sc * schunk;

    __shared__ float vlds[2][32][128];   // 32 KB

    const __hip_bfloat16* ap = abfT + ((size_t)b * BQ + row) * SEQ + sbase + kg * 8;
    const float* vb = values + ((size_t)b * SEQ + sbase) * H + h0;

    const int nk = schunk / 32;

    #define STAGE(buf, k0)                                                     \
        {                                                                      \
            _Pragma("unroll")                                                  \
            for (int ii = 0; ii < 4; ++ii) {                                   \
                int elem = w * 1024 + ii * 256 + l * 4;                        \
                int k    = elem >> 7;                                          \
                int cc   = elem & 127;                                         \
                int csw  = cc ^ ((k >> 3) << 4);                               \
                const float* src = vb + (size_t)((k0) + k) * H + csw;          \
                gload_lds16(src, (void*)(&vlds[buf][0][0] + w * 1024 + ii * 256)); \
            }                                                                  \
        }

    f32x4 acc[4][2] = {};
    STAGE(0, 0);
    __syncthreads();

    for (int ks = 0; ks < nk; ++ks) {
        const int buf = ks & 1;
        if (ks + 1 < nk) STAGE(buf ^ 1, (ks + 1) * 32);
        const int k0 = ks * 32;
        bf16x8 a[4];
        #pragma unroll
        for (int q = 0; q < 4; ++q)
            a[q] = *reinterpret_cast<const bf16x8*>(ap + (size_t)q * 16 * SEQ + k0);
        #pragma unroll
        for (int j = 0; j < 2; ++j) {
            const int col = (w * 32 + j * 16 + row) ^ (kg << 4);
            float b8[8];
            #pragma unroll
            for (int e = 0; e < 8; ++e)
                b8[e] = vlds[buf][kg * 8 + e][col];
            bf16x8 bhi, blo;
            split_bf16(b8, bhi, blo);
            #pragma unroll
            for (int q = 0; q < 4; ++q) {
                acc[q][j] = __builtin_amdgcn_mfma_f32_16x16x32_bf16(a[q], bhi, acc[q][j], 0, 0, 0);
                acc[q][j] = __builtin_amdgcn_mfma_f32_16x16x32_bf16(a[q], blo, acc[q][j], 0, 0, 0);
            }
        }
        __syncthreads();
    }
    #undef STAGE

    float* tp = Tpart + ((size_t)sc * NB + b) * BQ * H;
    #pragma unroll
    for (int q = 0; q < 4; ++q) {
        #pragma unroll
        for (int j = 0; j < 2; ++j) {
            int h = h0 + w * 32 + j * 16 + row;
            #pragma unroll
            for (int r = 0; r < 4; ++r) {
                int qi = q * 16 + kg * 4 + r;
                tp[(size_t)qi * H + h] = acc[q][j][r];
            }
        }
    }
}

// ---------------------------------------------------------------------------
// In-place partial reduction: Tpart[0][i] = sum_p Tpart[p][i]
// ---------------------------------------------------------------------------
template<int SC>
__global__ __launch_bounds__(256)
void tsum_kernel(float* __restrict__ Tpart)
{
    const size_t stride = (size_t)NB * BQ * H;
    size_t i = ((size_t)blockIdx.x * 256 + threadIdx.x) * 4;
    f32x4 s = *reinterpret_cast<const f32x4*>(Tpart + i);
    #pragma unroll
    for (int p = 1; p < SC; ++p)
        s += *reinterpret_cast<const f32x4*>(Tpart + p * stride + i);
    *reinterpret_cast<f32x4*>(Tpart + i) = s;
}

// ---------------------------------------------------------------------------
extern "C" void kernel_launch(void* const* d_in, const int* in_sizes, int n_in,
                              void* d_out, int out_size, void* d_ws, size_t ws_size,
                              hipStream_t stream)
{
    const float* queries = (const float*)d_in[0];
    const float* keys    = (const float*)d_in[1];
    const float* values  = (const float*)d_in[2];
    const float* Wq = (const float*)d_in[3];
    const float* bq = (const float*)d_in[4];
    const float* Wk = (const float*)d_in[5];
    const float* bk = (const float*)d_in[6];
    const float* Wv = (const float*)d_in[7];
    const float* bv = (const float*)d_in[8];

    float* out     = (float*)d_out;
    float* context = out;                          // 16*64*1024 f32
    float* attn    = out + (size_t)NB * BQ * H;    // 16*4096*64 f32

    const int SC = (ws_size >= (41ull << 20)) ? 8 : 2;

    char* ws = (char*)d_ws;
    float* q     = (float*)ws;                              // 4 MB  [0,4)
    float* WkT   = (float*)(ws + (4ull << 20));             // 4 MB  [4,8)
    __bf16* Nhi  = (__bf16*)(ws + (8ull << 20));            // 2 MB  [8,10)
    __bf16* Nlo  = (__bf16*)(ws + (10ull << 20));           // 2 MB  [10,12)
    float* Tpart = (float*)ws;                              // SC*4 MB (overlaps q/WkT/N, dead by tmat)
    __hip_bfloat16* abfT = (__hip_bfloat16*)(ws + (size_t)SC * (4ull << 20)); // 8 MB
    char* smalls = ws + (size_t)SC * (4ull << 20) + (8ull << 20);
    float* cvec  = (float*)smalls;                          // 4 KB
    float* gstat = (float*)(smalls + (64u << 10));          // 8 KB
    float* pmax  = (float*)(smalls + (128u << 10));         // 128 KB
    float* psum  = (float*)(smalls + (512u << 10));         // 128 KB

    const float scale = 0.03125f; // 1/sqrt(1024)

    // WkT = Wk^T
    transpose_k<<<dim3(16, 16), 256, 0, stream>>>(Wk, WkT);
    // q = queries @ Wq^T + bq   (split-K x2 in block)
    gemm_bt_512<0><<<dim3(16, 16), 512, 0, stream>>>(
        queries, Wq, bq, q, nullptr, nullptr, 1.0f);
    // N = (q @ Wk) * scale -> pre-split bf16 hi/lo
    gemm_bt_512<1><<<dim3(16, 16), 512, 0, stream>>>(
        q, WkT, nullptr, nullptr, Nhi, Nlo, scale);
    // c = (q . bk) * scale
    cvec_kernel<<<256, 256, 0, stream>>>(q, bk, cvec, scale);
    // scores + fused per-chunk softmax stats
    scores_mfma<<<512, 512, 0, stream>>>(keys, Nhi, Nlo, cvec, attn, pmax, psum);
    // combine + normalize
    sm_combine<<<NB, 64, 0, stream>>>(pmax, psum, gstat);
    sm_norm<<<dim3(32, NB), 256, 0, stream>>>(attn, gstat, abfT);
    // T partials = attn^T @ values
    if (SC == 8) tmat_mfma<8><<<8 * NB * 8, 256, 0, stream>>>(abfT, values, Tpart);
    else         tmat_mfma<2><<<8 * NB * 2, 256, 0, stream>>>(abfT, values, Tpart);
    // Tsum (in place into partial 0)
    if (SC == 8) tsum_kernel<8><<<1024, 256, 0, stream>>>(Tpart);
    else         tsum_kernel<2><<<1024, 256, 0, stream>>>(Tpart);
    // context = Tsum @ Wv^T + bv
    gemm_bt_512<0><<<dim3(16, 16), 512, 0, stream>>>(
        Tpart, Wv, bv, context, nullptr, nullptr, 1.0f);
}

// Round 13
// 281.417 us; speedup vs baseline: 1.1487x; 1.0120x over previous
//
#include <hip/hip_runtime.h>
#include <hip/hip_bf16.h>

#define H 1024
#define SEQ 4096
#define BQ 64   // Kq
#define NB 16   // batch

typedef float f32x4 __attribute__((ext_vector_type(4)));
typedef __bf16 bf16x8 __attribute__((ext_vector_type(8)));

__device__ __forceinline__ void split_bf16(const float* x, bf16x8& hi, bf16x8& lo)
{
    #pragma unroll
    for (int i = 0; i < 8; ++i) {
        float v = x[i];
        __bf16 h = (__bf16)v;
        hi[i] = h;
        lo[i] = (__bf16)(v - (float)h);
    }
}

__device__ __forceinline__ void gload_lds16(const float* g, void* lds)
{
    __builtin_amdgcn_global_load_lds(
        (const __attribute__((address_space(1))) void*)g,
        (__attribute__((address_space(3))) void*)lds, 16, 0, 0);
}

// ---------------------------------------------------------------------------
// 512-thread split-K(x2)-in-block MFMA GEMM (BNK-true): C = A @ B^T*scale+bias
// CVEC: additionally cvec[m] += cscale * sum_n C[m][n]*bk[n] (atomic).
// ---------------------------------------------------------------------------
template<bool CVEC>
__global__ __launch_bounds__(512)
void gemm_bt_512(const float* __restrict__ A, const float* __restrict__ Bm,
                 const float* __restrict__ bias, float* __restrict__ C,
                 float scale, const float* __restrict__ bk,
                 float* __restrict__ cvec, float cscale)
{
    const int m0 = blockIdx.x * 64;
    const int n0 = blockIdx.y * 64;
    const int t   = threadIdx.x;
    const int w   = t >> 6;
    const int wm  = w & 3;      // m-subtile
    const int kh  = w >> 2;     // k-half
    const int l   = t & 63;
    const int row = l & 15;
    const int kg  = l >> 4;

    const float* ap = A + (size_t)(m0 + wm * 16 + row) * H + kh * 512 + kg * 8;
    const float* bp = Bm + (size_t)(n0 + row) * H + kh * 512 + kg * 8;

    f32x4 acc[4] = {};
    for (int k0 = 0; k0 < 512; k0 += 32) {
        float a8[8];
        *reinterpret_cast<float4*>(&a8[0]) = *reinterpret_cast<const float4*>(ap + k0);
        *reinterpret_cast<float4*>(&a8[4]) = *reinterpret_cast<const float4*>(ap + k0 + 4);
        bf16x8 ahi, alo;
        split_bf16(a8, ahi, alo);
        #pragma unroll
        for (int j = 0; j < 4; ++j) {
            float b8[8];
            const float* bjp = bp + (size_t)j * 16 * H + k0;
            *reinterpret_cast<float4*>(&b8[0]) = *reinterpret_cast<const float4*>(bjp);
            *reinterpret_cast<float4*>(&b8[4]) = *reinterpret_cast<const float4*>(bjp + 4);
            bf16x8 bhi, blo;
            split_bf16(b8, bhi, blo);
            acc[j] = __builtin_amdgcn_mfma_f32_16x16x32_bf16(ahi, bhi, acc[j], 0, 0, 0);
            acc[j] = __builtin_amdgcn_mfma_f32_16x16x32_bf16(ahi, blo, acc[j], 0, 0, 0);
            acc[j] = __builtin_amdgcn_mfma_f32_16x16x32_bf16(alo, bhi, acc[j], 0, 0, 0);
        }
    }

    __shared__ f32x4 red[4][4][64];   // partials from kh==1 waves (16 KB)
    if (kh == 1) {
        #pragma unroll
        for (int j = 0; j < 4; ++j) red[wm][j][l] = acc[j];
    }
    __syncthreads();
    if (kh == 0) {
        float p[4] = {0.f, 0.f, 0.f, 0.f};
        #pragma unroll
        for (int j = 0; j < 4; ++j) {
            f32x4 s = acc[j] + red[wm][j][l];
            int n = n0 + j * 16 + row;
            float bb = bias ? bias[n] : 0.f;
            float bkv = CVEC ? bk[n] : 0.f;
            #pragma unroll
            for (int r = 0; r < 4; ++r) {
                int m = m0 + wm * 16 + kg * 4 + r;
                float o = s[r] * scale + bb;
                C[(size_t)m * H + n] = o;
                if (CVEC) p[r] += o * bkv;
            }
        }
        if (CVEC) {
            #pragma unroll
            for (int r = 0; r < 4; ++r) {
                #pragma unroll
                for (int off = 1; off < 16; off <<= 1)
                    p[r] += __shfl_xor(p[r], off);
            }
            if (row == 0) {
                #pragma unroll
                for (int r = 0; r < 4; ++r)
                    atomicAdd(&cvec[m0 + wm * 16 + kg * 4 + r], p[r] * cscale);
            }
        }
    }
}

// ---------------------------------------------------------------------------
// N-proj, B read strided directly from Wk[k][n]: N = (q @ Wk) * scale
// -> pre-split bf16 hi/lo [m][n]. 512-thr split-K(x2).
// ---------------------------------------------------------------------------
__global__ __launch_bounds__(512)
void ngemm_direct(const float* __restrict__ A, const float* __restrict__ Wk,
                  __bf16* __restrict__ Nhi, __bf16* __restrict__ Nlo, float scale)
{
    const int m0 = blockIdx.x * 64;
    const int n0 = blockIdx.y * 64;
    const int t   = threadIdx.x;
    const int w   = t >> 6;
    const int wm  = w & 3;
    const int kh  = w >> 2;
    const int l   = t & 63;
    const int row = l & 15;
    const int kg  = l >> 4;

    const float* ap = A + (size_t)(m0 + wm * 16 + row) * H + kh * 512 + kg * 8;
    const float* bp = Wk + (size_t)(kh * 512 + kg * 8) * H + n0 + row;

    f32x4 acc[4] = {};
    for (int k0 = 0; k0 < 512; k0 += 32) {
        float a8[8];
        *reinterpret_cast<float4*>(&a8[0]) = *reinterpret_cast<const float4*>(ap + k0);
        *reinterpret_cast<float4*>(&a8[4]) = *reinterpret_cast<const float4*>(ap + k0 + 4);
        bf16x8 ahi, alo;
        split_bf16(a8, ahi, alo);
        #pragma unroll
        for (int j = 0; j < 4; ++j) {
            float b8[8];
            #pragma unroll
            for (int e = 0; e < 8; ++e)
                b8[e] = bp[(size_t)(k0 + e) * H + j * 16];
            bf16x8 bhi, blo;
            split_bf16(b8, bhi, blo);
            acc[j] = __builtin_amdgcn_mfma_f32_16x16x32_bf16(ahi, bhi, acc[j], 0, 0, 0);
            acc[j] = __builtin_amdgcn_mfma_f32_16x16x32_bf16(ahi, blo, acc[j], 0, 0, 0);
            acc[j] = __builtin_amdgcn_mfma_f32_16x16x32_bf16(alo, bhi, acc[j], 0, 0, 0);
        }
    }

    __shared__ f32x4 red[4][4][64];
    if (kh == 1) {
        #pragma unroll
        for (int j = 0; j < 4; ++j) red[wm][j][l] = acc[j];
    }
    __syncthreads();
    if (kh == 0) {
        #pragma unroll
        for (int j = 0; j < 4; ++j) {
            f32x4 s = acc[j] + red[wm][j][l];
            int n = n0 + j * 16 + row;
            #pragma unroll
            for (int r = 0; r < 4; ++r) {
                int m = m0 + wm * 16 + kg * 4 + r;
                float v = s[r] * scale;
                __bf16 hi = (__bf16)v;
                Nhi[(size_t)m * H + n] = hi;
                Nlo[(size_t)m * H + n] = (__bf16)(v - (float)hi);
            }
        }
    }
}

// ---------------------------------------------------------------------------
// scores[b,s,qi] = sum_h keys[b,s,h]*N[b,qi,h] + c[b,qi]
// 64-k chunks; DOUBLE-buffered XOR-swizzled N LDS; ONE barrier per chunk;
// next chunk's keys+N register loads issued AFTER the barrier so they fly
// during the whole compute phase. 512 thr (8 waves x 16 s). Fused softmax
// partial stats. XCD swizzle.
// ---------------------------------------------------------------------------
__global__ __launch_bounds__(512, 4)
void scores_mfma(const float* __restrict__ keys,
                 const __bf16* __restrict__ Nhi, const __bf16* __restrict__ Nlo,
                 const float* __restrict__ cvec, float* __restrict__ scores,
                 float* __restrict__ pmax, float* __restrict__ psum)
{
    const int id = blockIdx.x;          // 512 blocks
    const int x  = id & 7;
    const int m  = id >> 3;             // 0..63
    const int b  = 2 * x + (m >> 5);    // 2 batches per XCD
    const int ch = m & 31;
    const int s0 = ch * 128;

    const int t   = threadIdx.x;
    const int w   = t >> 6;             // 0..7
    const int l   = t & 63;
    const int row = l & 15;
    const int kg  = l >> 4;

    __shared__ __bf16 nshH[2][64][8][8];  // [buf][qi][slot][e] (16 KB)
    __shared__ __bf16 nshL[2][64][8][8];  // 16 KB
    __shared__ float redm[8][64];         // 2 KB

    const float* ka = keys + ((size_t)b * SEQ + s0 + w * 16 + row) * H + kg * 8;
    const __bf16* nhb = Nhi + (size_t)b * BQ * H;
    const __bf16* nlb = Nlo + (size_t)b * BQ * H;

    // staging: thread t covers (qi = t>>3, kb = t&7) of the 64x64 chunk
    const int sqi = t >> 3;
    const int skb = t & 7;
    const int ssl = skb ^ (sqi & 7);

    // prologue: chunk 0 into reg set 0
    float4 kr[2][4];
    bf16x8 nh[2], nl[2];
    #pragma unroll
    for (int ii = 0; ii < 2; ++ii) {
        kr[0][2 * ii + 0] = *reinterpret_cast<const float4*>(ka + ii * 32);
        kr[0][2 * ii + 1] = *reinterpret_cast<const float4*>(ka + ii * 32 + 4);
    }
    {
        size_t go = (size_t)sqi * H + skb * 8;
        nh[0] = *reinterpret_cast<const bf16x8*>(nhb + go);
        nl[0] = *reinterpret_cast<const bf16x8*>(nlb + go);
    }

    f32x4 acc[4] = {};
    #pragma unroll
    for (int c = 0; c < 16; ++c) {
        const int buf = c & 1;
        // write N(c) regs -> LDS[buf] (waits vmcnt for those loads)
        *reinterpret_cast<bf16x8*>(&nshH[buf][sqi][ssl][0]) = nh[buf];
        *reinterpret_cast<bf16x8*>(&nshL[buf][sqi][ssl][0]) = nl[buf];
        __syncthreads();
        // issue chunk c+1 loads AFTER the barrier -> in flight during compute
        if (c < 15) {
            const int kc = (c + 1) * 64;
            #pragma unroll
            for (int ii = 0; ii < 2; ++ii) {
                kr[buf ^ 1][2 * ii + 0] = *reinterpret_cast<const float4*>(ka + kc + ii * 32);
                kr[buf ^ 1][2 * ii + 1] = *reinterpret_cast<const float4*>(ka + kc + ii * 32 + 4);
            }
            size_t go = (size_t)sqi * H + kc + skb * 8;
            nh[buf ^ 1] = *reinterpret_cast<const bf16x8*>(nhb + go);
            nl[buf ^ 1] = *reinterpret_cast<const bf16x8*>(nlb + go);
        }
        // compute chunk c from kr[buf] + LDS[buf]
        #pragma unroll
        for (int ii = 0; ii < 2; ++ii) {
            float a8[8];
            *reinterpret_cast<float4*>(&a8[0]) = kr[buf][2 * ii + 0];
            *reinterpret_cast<float4*>(&a8[4]) = kr[buf][2 * ii + 1];
            bf16x8 ahi, alo;
            split_bf16(a8, ahi, alo);
            const int kb = ii * 4 + kg;
            const int slot = kb ^ (row & 7);
            #pragma unroll
            for (int j = 0; j < 4; ++j) {
                const int qi = j * 16 + row;
                bf16x8 bhi = *reinterpret_cast<const bf16x8*>(&nshH[buf][qi][slot][0]);
                bf16x8 blo = *reinterpret_cast<const bf16x8*>(&nshL[buf][qi][slot][0]);
                acc[j] = __builtin_amdgcn_mfma_f32_16x16x32_bf16(ahi, bhi, acc[j], 0, 0, 0);
                acc[j] = __builtin_amdgcn_mfma_f32_16x16x32_bf16(ahi, blo, acc[j], 0, 0, 0);
                acc[j] = __builtin_amdgcn_mfma_f32_16x16x32_bf16(alo, bhi, acc[j], 0, 0, 0);
            }
        }
    }

    // epilogue: add cvec, write scores
    #pragma unroll
    for (int j = 0; j < 4; ++j) {
        int qi = j * 16 + row;
        float cv = cvec[b * BQ + qi];
        #pragma unroll
        for (int r = 0; r < 4; ++r) {
            acc[j][r] += cv;
            int s = s0 + w * 16 + kg * 4 + r;
            scores[((size_t)b * SEQ + s) * BQ + qi] = acc[j][r];
        }
    }
    // fused partial stats over this block's 128 s-rows
    float mj[4];
    #pragma unroll
    for (int j = 0; j < 4; ++j) {
        float mm = fmaxf(fmaxf(acc[j][0], acc[j][1]), fmaxf(acc[j][2], acc[j][3]));
        mm = fmaxf(mm, __shfl_xor(mm, 16));
        mm = fmaxf(mm, __shfl_xor(mm, 32));
        mj[j] = mm;
    }
    __syncthreads();
    if (kg == 0) {
        #pragma unroll
        for (int j = 0; j < 4; ++j) redm[w][j * 16 + row] = mj[j];
    }
    __syncthreads();
    float Mj[4];
    #pragma unroll
    for (int j = 0; j < 4; ++j) {
        const int qi = j * 16 + row;
        float M = redm[0][qi];
        #pragma unroll
        for (int ww = 1; ww < 8; ++ww) M = fmaxf(M, redm[ww][qi]);
        Mj[j] = M;
    }
    float sj[4];
    #pragma unroll
    for (int j = 0; j < 4; ++j) {
        float s = 0.f;
        #pragma unroll
        for (int r = 0; r < 4; ++r) s += __expf(acc[j][r] - Mj[j]);
        s += __shfl_xor(s, 16);
        s += __shfl_xor(s, 32);
        sj[j] = s;
    }
    __syncthreads();
    if (kg == 0) {
        #pragma unroll
        for (int j = 0; j < 4; ++j) redm[w][j * 16 + row] = sj[j];
    }
    __syncthreads();
    if (w == 0 && kg == 0) {
        #pragma unroll
        for (int j = 0; j < 4; ++j) {
            const int qi = j * 16 + row;
            float ss = 0.f;
            #pragma unroll
            for (int ww = 0; ww < 8; ++ww) ss += redm[ww][qi];
            pmax[((size_t)b * 32 + ch) * 64 + qi] = Mj[j];
            psum[((size_t)b * 32 + ch) * 64 + qi] = ss;
        }
    }
}

// ---------------------------------------------------------------------------
// normalize in place (inline global-stat combine) + bf16 transposed copy
// ---------------------------------------------------------------------------
__global__ __launch_bounds__(256)
void sm_norm(float* __restrict__ attn, const float* __restrict__ pmax,
             const float* __restrict__ psum, __hip_bfloat16* __restrict__ abfT)
{
    __shared__ float tile[64][133];
    const int b  = blockIdx.y;
    const int ch = blockIdx.x;
    const int t  = threadIdx.x;
    const int qi = t & 63;
    const int g  = t >> 6;

    // inline combine of 32 chunk-stats for this (b,qi)
    float M = -1e30f;
    #pragma unroll 4
    for (int c = 0; c < 32; ++c)
        M = fmaxf(M, pmax[((size_t)b * 32 + c) * 64 + qi]);
    float ssum = 0.f;
    #pragma unroll 4
    for (int c = 0; c < 32; ++c)
        ssum += psum[((size_t)b * 32 + c) * 64 + qi] *
                __expf(pmax[((size_t)b * 32 + c) * 64 + qi] - M);
    const float inv = 1.f / ssum;

    float* sb = attn + ((size_t)b * SEQ + ch * 128) * BQ;
    #pragma unroll 8
    for (int i = 0; i < 32; ++i) {
        int sl = g + i * 4;
        size_t idx = (size_t)sl * BQ + qi;
        float w = __expf(sb[idx] - M) * inv;
        sb[idx] = w;
        tile[qi][sl] = w;
    }
    __syncthreads();
    const int qo = t >> 2;
    const int c  = (t & 3) * 32;
    __hip_bfloat16* dst = abfT + ((size_t)(b * BQ + qo)) * SEQ + ch * 128 + c;
    #pragma unroll
    for (int v = 0; v < 4; ++v) {
        bf16x8 w8;
        #pragma unroll
        for (int e = 0; e < 8; ++e)
            w8[e] = (__bf16)tile[qo][c + v * 8 + e];
        *reinterpret_cast<bf16x8*>(dst + v * 8) = w8;
    }
}

// ---------------------------------------------------------------------------
// Tpart[sc][b][qi][h] = sum_{s in chunk} abfT[b,qi,s] * values[b,s,h]
// values staged via global_load_lds (dbuf, pre-swizzled source col).
// ---------------------------------------------------------------------------
template<int SC>
__global__ __launch_bounds__(256)
void tmat_mfma(const __hip_bfloat16* __restrict__ abfT,
               const float* __restrict__ values,
               float* __restrict__ Tpart)
{
    const int i  = blockIdx.x;
    const int h0 = ((i >> 3) & 7) * 128;
    const int g  = (i & 7) + 8 * (i >> 6);
    const int b  = g / SC;
    const int sc = g % SC;
    const int schunk = SEQ / SC;

    const int w   = threadIdx.x >> 6;
    const int l   = threadIdx.x & 63;
    const int row = l & 15;
    const int kg  = l >> 4;
    const int sbase = sc * schunk;

    __shared__ float vlds[2][32][128];   // 32 KB

    const __hip_bfloat16* ap = abfT + ((size_t)b * BQ + row) * SEQ + sbase + kg * 8;
    const float* vb = values + ((size_t)b * SEQ + sbase) * H + h0;

    const int nk = schunk / 32;

    #define STAGE(buf, k0)                                                     \
        {                                                                      \
            _Pragma("unroll")                                                  \
            for (int ii = 0; ii < 4; ++ii) {                                   \
                int elem = w * 1024 + ii * 256 + l * 4;                        \
                int k    = elem >> 7;                                          \
                int cc   = elem & 127;                                         \
                int csw  = cc ^ ((k >> 3) << 4);                               \
                const float* src = vb + (size_t)((k0) + k) * H + csw;          \
                gload_lds16(src, (void*)(&vlds[buf][0][0] + w * 1024 + ii * 256)); \
            }                                                                  \
        }

    f32x4 acc[4][2] = {};
    STAGE(0, 0);
    __syncthreads();

    for (int ks = 0; ks < nk; ++ks) {
        const int buf = ks & 1;
        if (ks + 1 < nk) STAGE(buf ^ 1, (ks + 1) * 32);
        const int k0 = ks * 32;
        bf16x8 a[4];
        #pragma unroll
        for (int q = 0; q < 4; ++q)
            a[q] = *reinterpret_cast<const bf16x8*>(ap + (size_t)q * 16 * SEQ + k0);
        #pragma unroll
        for (int j = 0; j < 2; ++j) {
            const int col = (w * 32 + j * 16 + row) ^ (kg << 4);
            float b8[8];
            #pragma unroll
            for (int e = 0; e < 8; ++e)
                b8[e] = vlds[buf][kg * 8 + e][col];
            bf16x8 bhi, blo;
            split_bf16(b8, bhi, blo);
            #pragma unroll
            for (int q = 0; q < 4; ++q) {
                acc[q][j] = __builtin_amdgcn_mfma_f32_16x16x32_bf16(a[q], bhi, acc[q][j], 0, 0, 0);
                acc[q][j] = __builtin_amdgcn_mfma_f32_16x16x32_bf16(a[q], blo, acc[q][j], 0, 0, 0);
            }
        }
        __syncthreads();
    }
    #undef STAGE

    float* tp = Tpart + ((size_t)sc * NB + b) * BQ * H;
    #pragma unroll
    for (int q = 0; q < 4; ++q) {
        #pragma unroll
        for (int j = 0; j < 2; ++j) {
            int h = h0 + w * 32 + j * 16 + row;
            #pragma unroll
            for (int r = 0; r < 4; ++r) {
                int qi = q * 16 + kg * 4 + r;
                tp[(size_t)qi * H + h] = acc[q][j][r];
            }
        }
    }
}

// ---------------------------------------------------------------------------
// In-place partial reduction: Tpart[0][i] = sum_p Tpart[p][i]
// ---------------------------------------------------------------------------
template<int SC>
__global__ __launch_bounds__(256)
void tsum_kernel(float* __restrict__ Tpart)
{
    const size_t stride = (size_t)NB * BQ * H;
    size_t i = ((size_t)blockIdx.x * 256 + threadIdx.x) * 4;
    f32x4 s = *reinterpret_cast<const f32x4*>(Tpart + i);
    #pragma unroll
    for (int p = 1; p < SC; ++p)
        s += *reinterpret_cast<const f32x4*>(Tpart + p * stride + i);
    *reinterpret_cast<f32x4*>(Tpart + i) = s;
}

// ---------------------------------------------------------------------------
extern "C" void kernel_launch(void* const* d_in, const int* in_sizes, int n_in,
                              void* d_out, int out_size, void* d_ws, size_t ws_size,
                              hipStream_t stream)
{
    const float* queries = (const float*)d_in[0];
    const float* keys    = (const float*)d_in[1];
    const float* values  = (const float*)d_in[2];
    const float* Wq = (const float*)d_in[3];
    const float* bq = (const float*)d_in[4];
    const float* Wk = (const float*)d_in[5];
    const float* bk = (const float*)d_in[6];
    const float* Wv = (const float*)d_in[7];
    const float* bv = (const float*)d_in[8];

    float* out     = (float*)d_out;
    float* context = out;                          // 16*64*1024 f32
    float* attn    = out + (size_t)NB * BQ * H;    // 16*4096*64 f32

    const int SC = (ws_size >= (41ull << 20)) ? 8 : 2;

    char* ws = (char*)d_ws;
    float* q     = (float*)ws;                              // 4 MB  [0,4)
    __bf16* Nhi  = (__bf16*)(ws + (8ull << 20));            // 2 MB  [8,10)
    __bf16* Nlo  = (__bf16*)(ws + (10ull << 20));           // 2 MB  [10,12)
    float* Tpart = (float*)ws;                              // SC*4 MB (overlaps q/N, dead by tmat)
    __hip_bfloat16* abfT = (__hip_bfloat16*)(ws + (size_t)SC * (4ull << 20)); // 8 MB
    char* smalls = ws + (size_t)SC * (4ull << 20) + (8ull << 20);
    float* cvec  = (float*)smalls;                          // 4 KB
    float* pmax  = (float*)(smalls + (128u << 10));         // 128 KB
    float* psum  = (float*)(smalls + (512u << 10));         // 128 KB

    const float scale = 0.03125f; // 1/sqrt(1024)

    // cvec accumulated atomically in q-GEMM epilogue
    hipMemsetAsync(cvec, 0, (size_t)NB * BQ * sizeof(float), stream);
    // q = queries @ Wq^T + bq  (+ cvec = scale*(q . bk))
    gemm_bt_512<true><<<dim3(16, 16), 512, 0, stream>>>(
        queries, Wq, bq, q, 1.0f, bk, cvec, scale);
    // N = (q @ Wk) * scale -> pre-split bf16 hi/lo (Wk read strided, no transpose)
    ngemm_direct<<<dim3(16, 16), 512, 0, stream>>>(q, Wk, Nhi, Nlo, scale);
    // scores + fused per-chunk softmax stats
    scores_mfma<<<512, 512, 0, stream>>>(keys, Nhi, Nlo, cvec, attn, pmax, psum);
    // normalize (inline stat combine) + bf16 transposed copy
    sm_norm<<<dim3(32, NB), 256, 0, stream>>>(attn, pmax, psum, abfT);
    // T partials = attn^T @ values
    if (SC == 8) tmat_mfma<8><<<8 * NB * 8, 256, 0, stream>>>(abfT, values, Tpart);
    else         tmat_mfma<2><<<8 * NB * 2, 256, 0, stream>>>(abfT, values, Tpart);
    // Tsum (in place into partial 0)
    if (SC == 8) tsum_kernel<8><<<1024, 256, 0, stream>>>(Tpart);
    else         tsum_kernel<2><<<1024, 256, 0, stream>>>(Tpart);
    // context = Tsum @ Wv^T + bv
    gemm_bt_512<false><<<dim3(16, 16), 512, 0, stream>>>(
        Tpart, Wv, bv, context, 1.0f, nullptr, nullptr, 0.f);
}